// Round 3
// baseline (1119.184 us; speedup 1.0000x reference)
//
#include <hip/hip_runtime.h>
#include <hip/hip_bf16.h>

typedef __hip_bfloat16 bf16;
typedef __attribute__((ext_vector_type(8))) short short8;
typedef __attribute__((ext_vector_type(4))) float floatx4;

#define NN     131072
#define NEDGE  1048576
#define BG     1024
#define LAYERS 3
#define TG     8      // graphs per tail block

// bf16 split helpers (RNE)
__device__ __forceinline__ short f2bf_s(float f){
    union { float f; unsigned u; } x; x.f = f;
    unsigned r = x.u + 0x7fffu + ((x.u >> 16) & 1u);
    return (short)(r >> 16);
}
__device__ __forceinline__ float bf2f_s(short s){
    union { unsigned u; float f; } x; x.u = ((unsigned)(unsigned short)s) << 16;
    return x.f;
}
__device__ __forceinline__ void acc4(const unsigned short* p,
                                     float& a0, float& a1, float& a2, float& a3){
    ushort4 u = *(const ushort4*)p;
    a0 += bf2f_s((short)u.x); a1 += bf2f_s((short)u.y);
    a2 += bf2f_s((short)u.z); a3 += bf2f_s((short)u.w);
}

// ------------------------------------------------------------------
// CSR build (deterministic fill via rank captured in k_hist).
// k_zero also carries the folded outer MLP of the PREVIOUS side's
// last layer (pooled_prev != nullptr on side 1 only).
// ------------------------------------------------------------------
__global__ __launch_bounds__(256) void k_zero(int* __restrict__ cnt,
    const float* __restrict__ pooled_prev, const float* __restrict__ owp,
    const float* __restrict__ obp, float* __restrict__ feats_prev)
{
    int i = blockIdx.x*256 + threadIdx.x;
    if (i < NN) cnt[i] = 0;
    if (pooled_prev && blockIdx.x < 256) {
        int bb = i >> 6, j = i & 63;
        const float* pr = pooled_prev + bb*64;
        float a = obp[j];
        for (int k = 0; k < 64; k++) a = fmaf(pr[k], owp[k*64 + j], a);
        feats_prev[bb*192 + 128 + j] = fmaxf(a, 0.f);
    }
}

__global__ __launch_bounds__(256) void k_hist(const int* __restrict__ ei,
                                              int* __restrict__ cnt,
                                              int* __restrict__ rank)
{
    int e = blockIdx.x*256 + threadIdx.x;
    rank[e] = atomicAdd(cnt + ei[NEDGE + e], 1);
}

__global__ __launch_bounds__(256) void k_scan1(const int* __restrict__ cnt,
    int* __restrict__ rowptr, int* __restrict__ bsum)
{
    __shared__ int sd[256];
    int t = threadIdx.x;
    int base = blockIdx.x*1024 + t*4;
    int c0 = cnt[base], c1 = cnt[base+1], c2 = cnt[base+2], c3 = cnt[base+3];
    int tsum = c0 + c1 + c2 + c3;
    sd[t] = tsum;
    __syncthreads();
    for (int off = 1; off < 256; off <<= 1) {
        int v = (t >= off) ? sd[t-off] : 0;
        __syncthreads();
        sd[t] += v;
        __syncthreads();
    }
    int excl = sd[t] - tsum;
    rowptr[base]   = excl;
    rowptr[base+1] = excl + c0;
    rowptr[base+2] = excl + c0 + c1;
    rowptr[base+3] = excl + c0 + c1 + c2;
    if (t == 255) bsum[blockIdx.x] = sd[255];
}

__global__ __launch_bounds__(128) void k_scan2(const int* __restrict__ bsum,
    int* __restrict__ boff, int* __restrict__ rowptr)
{
    __shared__ int sd[128];
    int t = threadIdx.x;
    int v0 = bsum[t];
    sd[t] = v0;
    __syncthreads();
    for (int off = 1; off < 128; off <<= 1) {
        int v = (t >= off) ? sd[t-off] : 0;
        __syncthreads();
        sd[t] += v;
        __syncthreads();
    }
    boff[t] = sd[t] - v0;
    if (t == 0) rowptr[NN] = NEDGE;
}

__global__ __launch_bounds__(256) void k_scan3(int* __restrict__ rowptr,
    const int* __restrict__ boff)
{
    int i = blockIdx.x*256 + threadIdx.x;
    rowptr[i] += boff[i >> 10];
}

__global__ __launch_bounds__(256) void k_fill(const int* __restrict__ ei,
    const int* __restrict__ rowptr, const int* __restrict__ rank,
    int* __restrict__ col)
{
    int e = blockIdx.x*256 + threadIdx.x;
    int s = ei[e];
    int d = ei[NEDGE + e];
    col[rowptr[d] + rank[e]] = s;
}

// ------------------------------------------------------------------
// fp32 -> bf16 shadow of node features (vectorized) + zero stats3/pooled3
// ------------------------------------------------------------------
__global__ __launch_bounds__(256) void k_cvt(const float* __restrict__ x,
                                             bf16* __restrict__ xh,
                                             float* __restrict__ zbuf)
{
    int i = blockIdx.x*256 + threadIdx.x;   // 8192 blocks -> NN*64/4 threads
    float4 v = ((const float4*)x)[i];
    short4 o;
    o.x = f2bf_s(v.x); o.y = f2bf_s(v.y);
    o.z = f2bf_s(v.z); o.w = f2bf_s(v.w);
    ((short4*)xh)[i] = o;
    if (i < 3*128 + 3*BG*64) zbuf[i] = 0.f;
}

// ------------------------------------------------------------------
// Weight prep (once/launch): Wt[n][k] = W[k][n], split bf16 hi/lo.
// ------------------------------------------------------------------
__global__ __launch_bounds__(256) void k_wprep(
    const float* __restrict__ gw1, const float* __restrict__ gw2,
    const float* __restrict__ iw,
    short* __restrict__ w1h, short* __restrict__ w1l,
    short* __restrict__ w2h, short* __restrict__ w2l,
    short* __restrict__ wih, short* __restrict__ wil)
{
    int i = blockIdx.x*256 + threadIdx.x;
    if (i >= 3*LAYERS*4096) return;
    int msel = i / (LAYERS*4096);
    int rem  = i % (LAYERS*4096);
    int l = rem >> 12, idx = rem & 4095;
    int n = idx >> 6, k = idx & 63;
    const float* src = (msel==0) ? gw1 : (msel==1) ? gw2 : iw;
    float v = src[l*4096 + k*64 + n];
    short hi = f2bf_s(v);
    short lo = f2bf_s(v - bf2f_s(hi));
    short* dh = (msel==0) ? w1h : (msel==1) ? w2h : wih;
    short* dl = (msel==0) ? w1l : (msel==1) ? w2l : wil;
    dh[rem] = hi;
    dl[rem] = lo;
}

// ------------------------------------------------------------------
// FUSED aggregate + GIN MLP (+ folded outer MLP of previous layer on
// blocks 0-255 when pooled_prev != nullptr).
// M=16 nodes per wave (64/block): per-wave LDS 4608 B ->
// block LDS 20480 B -> 8 blocks/CU (32 waves/CU occupancy cap).
// Gather geometry identical to the proven r0 config: 16 lanes/row,
// 8 B/lane, chunk-4 inner loop with 4 independent accumulator quads.
// ------------------------------------------------------------------
__global__ __launch_bounds__(256, 8) void k_agg_gin(
    const bf16* __restrict__ xh,
    const int* __restrict__ rowptr, const int* __restrict__ col,
    const float* __restrict__ epsp,
    const short* __restrict__ w1h, const short* __restrict__ w1l,
    const float* __restrict__ b1,
    const short* __restrict__ w2h, const short* __restrict__ w2l,
    const float* __restrict__ b2,
    float* __restrict__ big, float* __restrict__ stats,
    const float* __restrict__ pooled_prev, const float* __restrict__ owp,
    const float* __restrict__ obp, float* __restrict__ feats, int coffp)
{
    __shared__ __align__(16) char buf[4][4608];
    __shared__ float red[2][4][64];
    int tid = threadIdx.x, wv = tid >> 6, lane = tid & 63;
    int q = lane >> 4, m = lane & 15;
    int nb = blockIdx.x*64 + wv*16;
    short* Sh = (short*)buf[wv];
    short* Sl = Sh + 1152;      // 16*72
    float ep = 1.0f + *epsp;

    // folded outer MLP of previous layer
    if (pooled_prev && blockIdx.x < 256) {
        int g = blockIdx.x*256 + tid;
        int bb = g >> 6, j = g & 63;
        const float* pr = pooled_prev + bb*64;
        float a = obp[j];
        for (int k = 0; k < 64; k++) a = fmaf(pr[k], owp[k*64 + j], a);
        feats[bb*192 + coffp + j] = fmaxf(a, 0.f);
    }

    // ---- Phase 1: group-per-node gather (16 rows, 4 passes of 4) ----
    int gv = rowptr[nb + (lane < 17 ? lane : 16)];
    int fo = m * 4;              // ushort feature offset (8 B per lane)
    const unsigned short* xt = (const unsigned short*)xh;

    for (int i = 0; i < 4; i++) {
        int row = i*4 + q;
        int rs = __shfl(gv, row, 64);
        int re = __shfl(gv, row+1, 64);
        float a0=0.f,a1=0.f,a2=0.f,a3=0.f;
        float e0=0.f,e1=0.f,e2=0.f,e3=0.f;
        float g0=0.f,g1=0.f,g2=0.f,g3=0.f;
        float h0=0.f,h1=0.f,h2=0.f,h3=0.f;
        int r = rs;
        for (; r + 4 <= re; r += 4) {
            int ca = col[r], cb = col[r+1], cc = col[r+2], cd = col[r+3];
            acc4(xt + (((size_t)ca) << 6) + fo, a0,a1,a2,a3);
            acc4(xt + (((size_t)cb) << 6) + fo, e0,e1,e2,e3);
            acc4(xt + (((size_t)cc) << 6) + fo, g0,g1,g2,g3);
            acc4(xt + (((size_t)cd) << 6) + fo, h0,h1,h2,h3);
        }
        for (; r < re; r++)
            acc4(xt + (((size_t)col[r]) << 6) + fo, a0,a1,a2,a3);
        a0 += e0 + g0 + h0;
        a1 += e1 + g1 + h1;
        a2 += e2 + g2 + h2;
        a3 += e3 + g3 + h3;
        ushort4 sv = *(const ushort4*)(xt + (((size_t)(nb+row)) << 6) + fo);
        a0 = fmaf(ep, bf2f_s((short)sv.x), a0);
        a1 = fmaf(ep, bf2f_s((short)sv.y), a1);
        a2 = fmaf(ep, bf2f_s((short)sv.z), a2);
        a3 = fmaf(ep, bf2f_s((short)sv.w), a3);
        short4 hh, ll;
        hh.x = f2bf_s(a0); ll.x = f2bf_s(a0 - bf2f_s(hh.x));
        hh.y = f2bf_s(a1); ll.y = f2bf_s(a1 - bf2f_s(hh.y));
        hh.z = f2bf_s(a2); ll.z = f2bf_s(a2 - bf2f_s(hh.z));
        hh.w = f2bf_s(a3); ll.w = f2bf_s(a3 - bf2f_s(hh.w));
        *(short4*)(Sh + row*72 + fo) = hh;
        *(short4*)(Sl + row*72 + fo) = ll;
    }
    __syncthreads();

    // ---- Phase 2: GEMM1 (A from LDS), M=16 ----
    short8 Ah[2], Al[2];
    #pragma unroll
    for (int kc=0; kc<2; kc++){
        Ah[kc] = *(const short8*)(Sh + m*72 + kc*32 + q*8);
        Al[kc] = *(const short8*)(Sl + m*72 + kc*32 + q*8);
    }
    floatx4 acc[4];
    #pragma unroll
    for (int nc=0;nc<4;nc++) acc[nc] = (floatx4){0.f,0.f,0.f,0.f};
    #pragma unroll
    for (int nc=0;nc<4;nc++){
      #pragma unroll
      for (int kc=0;kc<2;kc++){
        short8 bh = *(const short8*)(w1h + (nc*16+m)*64 + kc*32 + q*8);
        short8 bl = *(const short8*)(w1l + (nc*16+m)*64 + kc*32 + q*8);
        acc[nc] = __builtin_amdgcn_mfma_f32_16x16x32_bf16(Ah[kc], bh, acc[nc],0,0,0);
        acc[nc] = __builtin_amdgcn_mfma_f32_16x16x32_bf16(Al[kc], bh, acc[nc],0,0,0);
        acc[nc] = __builtin_amdgcn_mfma_f32_16x16x32_bf16(Ah[kc], bl, acc[nc],0,0,0);
      }
    }

    // epilogue 1: bias + relu, split back into LDS
    #pragma unroll
    for (int nc=0;nc<4;nc++){
      float bia = b1[nc*16+m];
      #pragma unroll
      for (int r=0;r<4;r++){
        float v = fmaxf(acc[nc][r] + bia, 0.f);
        int row = q*4 + r, cl = nc*16 + m;
        short hb = f2bf_s(v);
        Sh[row*72+cl] = hb;
        Sl[row*72+cl] = f2bf_s(v - bf2f_s(hb));
      }
    }
    __syncthreads();

    // GEMM2
    short8 A2h[2], A2l[2];
    #pragma unroll
    for (int kc=0; kc<2; kc++){
        A2h[kc] = *(const short8*)(Sh + m*72 + kc*32 + q*8);
        A2l[kc] = *(const short8*)(Sl + m*72 + kc*32 + q*8);
    }
    floatx4 acc2[4];
    #pragma unroll
    for (int nc=0;nc<4;nc++) acc2[nc] = (floatx4){0.f,0.f,0.f,0.f};
    #pragma unroll
    for (int nc=0;nc<4;nc++){
      #pragma unroll
      for (int kc=0;kc<2;kc++){
        short8 bh = *(const short8*)(w2h + (nc*16+m)*64 + kc*32 + q*8);
        short8 bl = *(const short8*)(w2l + (nc*16+m)*64 + kc*32 + q*8);
        acc2[nc] = __builtin_amdgcn_mfma_f32_16x16x32_bf16(A2h[kc], bh, acc2[nc],0,0,0);
        acc2[nc] = __builtin_amdgcn_mfma_f32_16x16x32_bf16(A2l[kc], bh, acc2[nc],0,0,0);
        acc2[nc] = __builtin_amdgcn_mfma_f32_16x16x32_bf16(A2h[kc], bl, acc2[nc],0,0,0);
      }
    }

    // epilogue 2: bias, store h2, BN stats
    #pragma unroll
    for (int nc=0;nc<4;nc++){
      float bia = b2[nc*16+m];
      float s = 0.f, s2 = 0.f;
      #pragma unroll
      for (int r=0;r<4;r++){
        float v = acc2[nc][r] + bia;
        big[(((size_t)(nb + q*4 + r)) << 6) + nc*16 + m] = v;
        s += v; s2 = fmaf(v, v, s2);
      }
      s  += __shfl_xor(s, 16, 64);  s  += __shfl_xor(s, 32, 64);
      s2 += __shfl_xor(s2,16, 64);  s2 += __shfl_xor(s2,32, 64);
      if (q == 0){ red[0][wv][nc*16+m] = s; red[1][wv][nc*16+m] = s2; }
    }
    __syncthreads();
    if (tid < 128){
      int which = tid >> 6, c = tid & 63;
      float a = red[which][0][c]+red[which][1][c]+red[which][2][c]+red[which][3][c];
      unsafeAtomicAdd(stats + which*64 + c, a);
    }
}

// ------------------------------------------------------------------
// MFMA BN-apply (params inline from stats) + inner MLP + fused pool.
// ------------------------------------------------------------------
__global__ __launch_bounds__(256) void k_bn_inner(
    const float* __restrict__ big, const float* __restrict__ stats,
    const float* __restrict__ gam, const float* __restrict__ bet,
    const short* __restrict__ wih, const short* __restrict__ wil,
    const float* __restrict__ bi,
    bf16* __restrict__ xh,
    const int* __restrict__ gidx, float* __restrict__ pooled)
{
    __shared__ __align__(16) char buf[4][9472];
    int tid = threadIdx.x, wv = tid >> 6, lane = tid & 63;
    int q = lane >> 4, m = lane & 15;
    int nb = blockIdx.x*128 + wv*32;
    short* Sh = (short*)buf[wv];
    short* Sl = Sh + 2304;

    // BN params inline (stats complete: previous dispatch)
    float mu  = stats[lane]    * (1.0f/NN);
    float ex2 = stats[64+lane] * (1.0f/NN);
    float var = ex2 - mu*mu;
    float sc  = gam[lane] * rsqrtf(var + 1e-5f);
    float sh  = bet[lane] - mu*sc;

    for (int rr = 0; rr < 32; rr++){
        float v = big[(((size_t)(nb+rr)) << 6) + lane];
        v = fmaxf(fmaf(v, sc, sh), 0.f);
        xh[(((size_t)(nb+rr)) << 6) + lane] = __float2bfloat16(v);
        short hb = f2bf_s(v);
        Sh[rr*72 + lane] = hb;
        Sl[rr*72 + lane] = f2bf_s(v - bf2f_s(hb));
    }
    __syncthreads();

    short8 A2h[2][2], A2l[2][2];
    #pragma unroll
    for (int mc=0; mc<2; mc++)
      #pragma unroll
      for (int kc=0; kc<2; kc++){
        A2h[mc][kc] = *(const short8*)(Sh + (mc*16+m)*72 + kc*32 + q*8);
        A2l[mc][kc] = *(const short8*)(Sl + (mc*16+m)*72 + kc*32 + q*8);
      }
    floatx4 acc[2][4];
    #pragma unroll
    for (int mc=0;mc<2;mc++)
      #pragma unroll
      for (int nc=0;nc<4;nc++) acc[mc][nc] = (floatx4){0.f,0.f,0.f,0.f};
    #pragma unroll
    for (int nc=0;nc<4;nc++){
      #pragma unroll
      for (int kc=0;kc<2;kc++){
        short8 bh = *(const short8*)(wih + (nc*16+m)*64 + kc*32 + q*8);
        short8 bl = *(const short8*)(wil + (nc*16+m)*64 + kc*32 + q*8);
        #pragma unroll
        for (int mc=0;mc<2;mc++){
          acc[mc][nc] = __builtin_amdgcn_mfma_f32_16x16x32_bf16(A2h[mc][kc], bh, acc[mc][nc],0,0,0);
          acc[mc][nc] = __builtin_amdgcn_mfma_f32_16x16x32_bf16(A2l[mc][kc], bh, acc[mc][nc],0,0,0);
          acc[mc][nc] = __builtin_amdgcn_mfma_f32_16x16x32_bf16(A2h[mc][kc], bl, acc[mc][nc],0,0,0);
        }
      }
    }
    __syncthreads();   // LDS reads done; safe to repurpose buf

    float* P = (float*)buf[wv];
    #pragma unroll
    for (int nc=0;nc<4;nc++){
      float bia = bi[nc*16+m];
      #pragma unroll
      for (int mc=0;mc<2;mc++)
        #pragma unroll
        for (int r=0;r<4;r++){
          float v = fmaxf(acc[mc][nc][r] + bia, 0.f);
          P[(mc*16 + q*4 + r)*66 + nc*16 + m] = v;
        }
    }
    __syncthreads();

    int gv = (lane < 32) ? gidx[nb + lane] : 0;
    int cur = __shfl(gv, 0, 64);
    float a = 0.f;
    for (int rr = 0; rr < 32; rr++){
        int g = __shfl(gv, rr, 64);
        if (g != cur){
            unsafeAtomicAdd(pooled + (size_t)cur*64 + lane, a);
            a = 0.f; cur = g;
        }
        a += P[rr*66 + lane];
    }
    unsafeAtomicAdd(pooled + (size_t)cur*64 + lane, a);
}

// ------------------------------------------------------------------
// Tail: TG graphs per block; corpus layer-2 outer computed inline.
// ------------------------------------------------------------------
__global__ __launch_bounds__(256) void k_tail(
    const float* __restrict__ qf, const float* __restrict__ cf,
    const float* __restrict__ pooled_c2,
    const float* __restrict__ ow2, const float* __restrict__ ob2,
    const float* __restrict__ cw1, const float* __restrict__ cb1,
    const float* __restrict__ cw2, const float* __restrict__ cb2,
    const float* __restrict__ sw1, const float* __restrict__ sb1,
    const float* __restrict__ sw2, const float* __restrict__ sb2,
    const float* __restrict__ nw,  const float* __restrict__ nwb,
    const float* __restrict__ nb,
    const float* __restrict__ mw1, const float* __restrict__ mb1,
    const float* __restrict__ mw2, const float* __restrict__ mb2,
    const float* __restrict__ alpha, const float* __restrict__ beta,
    float* __restrict__ out)
{
    __shared__ float cws[192*96];
    __shared__ float diff[TG][192];
    __shared__ float e1s[TG][64], e2s[TG][64];
    __shared__ float h1s[TG][96], h2s[TG][96];
    __shared__ float s1s[TG][16], s2s[TG][16], srep[TG][16];
    __shared__ float red[16][16][TG];

    int t = threadIdx.x;
    int b0 = blockIdx.x * TG;

    // inline corpus outer (layer 2): e2s = relu(pooled_c2 @ ow2 + ob2)
    {
        int b = t >> 5, o = (t & 31) * 2;
        const float* pr = pooled_c2 + (size_t)(b0 + b)*64;
        float a0 = ob2[o], a1 = ob2[o+1];
        for (int k = 0; k < 64; k++) {
            float p = pr[k];
            a0 = fmaf(p, ow2[k*64 + o], a0);
            a1 = fmaf(p, ow2[k*64 + o + 1], a1);
        }
        e2s[b][o]   = fmaxf(a0, 0.f);
        e2s[b][o+1] = fmaxf(a1, 0.f);
    }
    for (int i = t; i < 192*96; i += 256) cws[i] = cw1[i];
    __syncthreads();

    for (int i = t; i < TG*192; i += 256) {
        int b = i / 192, f = i % 192;
        float qv = qf[(b0+b)*192 + f];
        float cv = (f < 128) ? cf[(b0+b)*192 + f] : e2s[b][f-128];
        float d = qv - cv;
        diff[b][f] = __expf(-d*d);
        if (f >= 128) e1s[b][f-128] = qv;
    }
    __syncthreads();

    {
        int b = t >> 5, o = (t & 31) * 3;
        float a0 = cb1[o], a1 = cb1[o+1], a2 = cb1[o+2];
        for (int f = 0; f < 192; f++) {
            float d = diff[b][f];
            const float* w = cws + f*96 + o;
            a0 = fmaf(d, w[0], a0);
            a1 = fmaf(d, w[1], a1);
            a2 = fmaf(d, w[2], a2);
        }
        h1s[b][o] = fmaxf(a0, 0.f);
        h1s[b][o+1] = fmaxf(a1, 0.f);
        h1s[b][o+2] = fmaxf(a2, 0.f);
    }
    __syncthreads();
    for (int i = t; i < 96*96; i += 256) cws[i] = cw2[i];
    __syncthreads();
    {
        int b = t >> 5, o = (t & 31) * 3;
        float a0 = cb2[o], a1 = cb2[o+1], a2 = cb2[o+2];
        for (int f = 0; f < 96; f++) {
            float d = h1s[b][f];
            const float* w = cws + f*96 + o;
            a0 = fmaf(d, w[0], a0);
            a1 = fmaf(d, w[1], a1);
            a2 = fmaf(d, w[2], a2);
        }
        h2s[b][o] = tanhf(a0);
        h2s[b][o+1] = tanhf(a1);
        h2s[b][o+2] = tanhf(a2);
    }
    __syncthreads();
    if (t < TG*16) {
        int b = t >> 4, o = t & 15;
        float a = sb1[o];
        for (int f = 0; f < 96; f++) a = fmaf(h2s[b][f], sw1[f*16+o], a);
        s1s[b][o] = fmaxf(a, 0.f);
    }

    {
        int tt = t & 15, gq = t >> 4;
        int g0 = gq * 4;
        int lane = t & 63;
        float e1v[TG];
        #pragma unroll
        for (int b = 0; b < TG; b++) e1v[b] = e1s[b][lane];
        float v0[TG], v1[TG], v2[TG], v3[TG];
        #pragma unroll
        for (int b = 0; b < TG; b++) { v0[b]=0.f; v1[b]=0.f; v2[b]=0.f; v3[b]=0.f; }
        for (int f = 0; f < 64; f++) {
            const float* wp = nw + ((size_t)f*64 + g0)*16 + tt;
            float w0 = wp[0], w1 = wp[16], w2 = wp[32], w3 = wp[48];
            #pragma unroll
            for (int b = 0; b < TG; b++) {
                float e = __shfl(e1v[b], f, 64);
                v0[b] = fmaf(e, w0, v0[b]);
                v1[b] = fmaf(e, w1, v1[b]);
                v2[b] = fmaf(e, w2, v2[b]);
                v3[b] = fmaf(e, w3, v3[b]);
            }
        }
        #pragma unroll
        for (int b = 0; b < TG; b++) {
            float p = v0[b]*e2s[b][g0] + v1[b]*e2s[b][g0+1]
                    + v2[b]*e2s[b][g0+2] + v3[b]*e2s[b][g0+3];
            red[gq][tt][b] = p;
        }
    }
    __syncthreads();
    if (t < TG*16) {
        int b = t >> 4, tt = t & 15;
        float scv = 0.f;
        #pragma unroll
        for (int gq = 0; gq < 16; gq++) scv += red[gq][tt][b];
        float blk = nb[tt];
        for (int f = 0; f < 64; f++) blk = fmaf(e1s[b][f], nwb[tt*128 + f], blk);
        for (int f = 0; f < 64; f++) blk = fmaf(e2s[b][f], nwb[tt*128 + 64 + f], blk);
        srep[b][tt] = fmaxf(scv + blk, 0.f);
    }
    __syncthreads();
    if (t < TG*16) {
        int b = t >> 4, o = t & 15;
        float a = mb1[o];
        #pragma unroll
        for (int f = 0; f < 16; f++) a = fmaf(srep[b][f], mw1[f*16+o], a);
        s2s[b][o] = fmaxf(a, 0.f);
    }
    __syncthreads();
    if (t < TG) {
        float sco = sb2[0], sm = mb2[0];
        #pragma unroll
        for (int f = 0; f < 16; f++) {
            sco = fmaf(s1s[t][f], sw2[f], sco);
            sm  = fmaf(s2s[t][f], mw2[f], sm);
        }
        float score = 1.f / (1.f + __expf(-sco));
        float sim   = 1.f / (1.f + __expf(-sm));
        out[b0 + t] = alpha[0]*score + beta[0]*sim;
    }
}

// ------------------------------------------------------------------
extern "C" void kernel_launch(void* const* d_in, const int* in_sizes, int n_in,
                              void* d_out, int out_size, void* d_ws, size_t ws_size,
                              hipStream_t stream)
{
    const float* qx  = (const float*)d_in[0];
    const float* cx  = (const float*)d_in[1];
    const int*   qei = (const int*)d_in[2];
    const int*   cei = (const int*)d_in[3];
    const int*   qgi = (const int*)d_in[4];
    const int*   cgi = (const int*)d_in[5];
    const float* Wgw1 = (const float*)d_in[6];
    const float* Wgb1 = (const float*)d_in[7];
    const float* Wgw2 = (const float*)d_in[8];
    const float* Wgb2 = (const float*)d_in[9];
    const float* Wgam = (const float*)d_in[10];
    const float* Wbet = (const float*)d_in[11];
    const float* Weps = (const float*)d_in[12];
    const float* Wiw  = (const float*)d_in[13];
    const float* Wib  = (const float*)d_in[14];
    const float* Wow  = (const float*)d_in[15];
    const float* Wob  = (const float*)d_in[16];
    const float* Wcw1 = (const float*)d_in[17];
    const float* Wcb1 = (const float*)d_in[18];
    const float* Wcw2 = (const float*)d_in[19];
    const float* Wcb2 = (const float*)d_in[20];
    const float* Wsw1 = (const float*)d_in[21];
    const float* Wsb1 = (const float*)d_in[22];
    const float* Wsw2 = (const float*)d_in[23];
    const float* Wsb2 = (const float*)d_in[24];
    const float* Wnw  = (const float*)d_in[25];
    const float* Wnwb = (const float*)d_in[26];
    const float* Wnb  = (const float*)d_in[27];
    const float* Wmw1 = (const float*)d_in[28];
    const float* Wmb1 = (const float*)d_in[29];
    const float* Wmw2 = (const float*)d_in[30];
    const float* Wmb2 = (const float*)d_in[31];
    const float* Wal  = (const float*)d_in[32];
    const float* Wbe  = (const float*)d_in[33];

    float* F      = (float*)d_ws;
    float* big    = F;                        // N*64 (h2; rank aliases)
    float* zbuf   = F + 8388608;              // stats3(384) + pooled3(196608)
    float* stats3 = zbuf;
    float* pooled3= zbuf + 384;
    float* qf     = pooled3 + 3*BG*64;        // BG*192
    float* cf     = qf + 196608;              // BG*192
    int*   rowptr = (int*)(cf + 196608);      // NN+1
    int*   cnt    = rowptr + (NN + 1);        // NN (histogram)
    int*   col    = cnt + NN;                 // NEDGE
    int*   bsum   = col + NEDGE;              // 128
    int*   boff   = bsum + 128;               // 128
    bf16*  xh     = (bf16*)(boff + 128);      // N*64 bf16
    int*   rank   = (int*)big;                // NEDGE (dead during CSR build)
    uintptr_t wtb = (uintptr_t)(xh + (size_t)NN*64);
    wtb = (wtb + 63) & ~((uintptr_t)63);
    short* w1h = (short*)wtb;                 // 3*4096 each
    short* w1l = w1h + 3*4096;
    short* w2h = w1l + 3*4096;
    short* w2l = w2h + 3*4096;
    short* wih = w2l + 3*4096;
    short* wil = wih + 3*4096;

    k_wprep<<<144, 256, 0, stream>>>(Wgw1, Wgw2, Wiw, w1h, w1l, w2h, w2l, wih, wil);

    for (int side = 0; side < 2; side++) {
        const float* x0 = side ? cx  : qx;
        const int* ei   = side ? cei : qei;
        const int* gi   = side ? cgi : qgi;
        float* feats    = side ? cf  : qf;

        // side 1's k_zero also performs outer(l=2) for side 0 (qf cols 128..191)
        if (side == 0)
            k_zero<<<NN/256, 256, 0, stream>>>(cnt, nullptr, nullptr, nullptr, nullptr);
        else
            k_zero<<<NN/256, 256, 0, stream>>>(cnt, pooled3 + 2*BG*64,
                                               Wow + 2*4096, Wob + 2*64, qf);
        k_hist<<<NEDGE/256, 256, 0, stream>>>(ei, cnt, rank);
        k_scan1<<<128, 256, 0, stream>>>(cnt, rowptr, bsum);
        k_scan2<<<1, 128, 0, stream>>>(bsum, boff, rowptr);
        k_scan3<<<NN/256, 256, 0, stream>>>(rowptr, boff);
        k_fill<<<NEDGE/256, 256, 0, stream>>>(ei, rowptr, rank, col);

        k_cvt<<<NN*64/1024, 256, 0, stream>>>(x0, xh, zbuf);

        for (int l = 0; l < LAYERS; l++) {
            const float* pprev = (l == 0) ? nullptr : pooled3 + (size_t)(l-1)*BG*64;
            const float* owp   = (l == 0) ? nullptr : Wow + (l-1)*4096;
            const float* obp   = (l == 0) ? nullptr : Wob + (l-1)*64;
            k_agg_gin<<<NN/64, 256, 0, stream>>>(xh, rowptr, col, Weps + l,
                                                 w1h + l*4096, w1l + l*4096, Wgb1 + l*64,
                                                 w2h + l*4096, w2l + l*4096, Wgb2 + l*64,
                                                 big, stats3 + l*128,
                                                 pprev, owp, obp, feats, (l-1)*64);
            k_bn_inner<<<NN/128, 256, 0, stream>>>(big, stats3 + l*128,
                                                   Wgam + l*64, Wbet + l*64,
                                                   wih + l*4096, wil + l*4096,
                                                   Wib + l*64, xh, gi,
                                                   pooled3 + (size_t)l*BG*64);
        }
    }

    k_tail<<<BG/TG, 256, 0, stream>>>(qf, cf, pooled3 + 2*BG*64,
                                      Wow + 2*4096, Wob + 2*64,
                                      Wcw1, Wcb1, Wcw2, Wcb2,
                                      Wsw1, Wsb1, Wsw2, Wsb2,
                                      Wnw, Wnwb, Wnb, Wmw1, Wmb1, Wmw2, Wmb2,
                                      Wal, Wbe, (float*)d_out);
}

// Round 5
// 1079.100 us; speedup vs baseline: 1.0371x; 1.0371x over previous
//
#include <hip/hip_runtime.h>
#include <hip/hip_bf16.h>

typedef __hip_bfloat16 bf16;
typedef __attribute__((ext_vector_type(8))) short short8;
typedef __attribute__((ext_vector_type(4))) float floatx4;

#define NN     131072
#define NEDGE  1048576
#define BG     1024
#define LAYERS 3
#define TG     8      // graphs per tail block

// bf16 split helpers (RNE)
__device__ __forceinline__ short f2bf_s(float f){
    union { float f; unsigned u; } x; x.f = f;
    unsigned r = x.u + 0x7fffu + ((x.u >> 16) & 1u);
    return (short)(r >> 16);
}
__device__ __forceinline__ float bf2f_s(short s){
    union { unsigned u; float f; } x; x.u = ((unsigned)(unsigned short)s) << 16;
    return x.f;
}
__device__ __forceinline__ void acc4(const unsigned short* p,
                                     float& a0, float& a1, float& a2, float& a3){
    ushort4 u = *(const ushort4*)p;
    a0 += bf2f_s((short)u.x); a1 += bf2f_s((short)u.y);
    a2 += bf2f_s((short)u.z); a3 += bf2f_s((short)u.w);
}

// ------------------------------------------------------------------
// CSR build (deterministic fill via rank captured in k_hist).
// k_zero also carries the folded outer MLP of the PREVIOUS side's
// last layer (pooled_prev != nullptr on side 1 only).
// ------------------------------------------------------------------
__global__ __launch_bounds__(256) void k_zero(int* __restrict__ cnt,
    const float* __restrict__ pooled_prev, const float* __restrict__ owp,
    const float* __restrict__ obp, float* __restrict__ feats_prev)
{
    int i = blockIdx.x*256 + threadIdx.x;
    if (i < NN) cnt[i] = 0;
    if (pooled_prev && blockIdx.x < 256) {
        int bb = i >> 6, j = i & 63;
        const float* pr = pooled_prev + bb*64;
        float a = obp[j];
        for (int k = 0; k < 64; k++) a = fmaf(pr[k], owp[k*64 + j], a);
        feats_prev[bb*192 + 128 + j] = fmaxf(a, 0.f);
    }
}

__global__ __launch_bounds__(256) void k_hist(const int* __restrict__ ei,
                                              int* __restrict__ cnt,
                                              int* __restrict__ rank)
{
    int e = blockIdx.x*256 + threadIdx.x;
    rank[e] = atomicAdd(cnt + ei[NEDGE + e], 1);
}

__global__ __launch_bounds__(256) void k_scan1(const int* __restrict__ cnt,
    int* __restrict__ rowptr, int* __restrict__ bsum)
{
    __shared__ int sd[256];
    int t = threadIdx.x;
    int base = blockIdx.x*1024 + t*4;
    int c0 = cnt[base], c1 = cnt[base+1], c2 = cnt[base+2], c3 = cnt[base+3];
    int tsum = c0 + c1 + c2 + c3;
    sd[t] = tsum;
    __syncthreads();
    for (int off = 1; off < 256; off <<= 1) {
        int v = (t >= off) ? sd[t-off] : 0;
        __syncthreads();
        sd[t] += v;
        __syncthreads();
    }
    int excl = sd[t] - tsum;
    rowptr[base]   = excl;
    rowptr[base+1] = excl + c0;
    rowptr[base+2] = excl + c0 + c1;
    rowptr[base+3] = excl + c0 + c1 + c2;
    if (t == 255) bsum[blockIdx.x] = sd[255];
}

__global__ __launch_bounds__(128) void k_scan2(const int* __restrict__ bsum,
    int* __restrict__ boff, int* __restrict__ rowptr)
{
    __shared__ int sd[128];
    int t = threadIdx.x;
    int v0 = bsum[t];
    sd[t] = v0;
    __syncthreads();
    for (int off = 1; off < 128; off <<= 1) {
        int v = (t >= off) ? sd[t-off] : 0;
        __syncthreads();
        sd[t] += v;
        __syncthreads();
    }
    boff[t] = sd[t] - v0;
    if (t == 0) rowptr[NN] = NEDGE;
}

__global__ __launch_bounds__(256) void k_scan3(int* __restrict__ rowptr,
    const int* __restrict__ boff)
{
    int i = blockIdx.x*256 + threadIdx.x;
    rowptr[i] += boff[i >> 10];
}

__global__ __launch_bounds__(256) void k_fill(const int* __restrict__ ei,
    const int* __restrict__ rowptr, const int* __restrict__ rank,
    int* __restrict__ col)
{
    int e = blockIdx.x*256 + threadIdx.x;
    int s = ei[e];
    int d = ei[NEDGE + e];
    col[rowptr[d] + rank[e]] = s;
}

// ------------------------------------------------------------------
// fp32 -> bf16 shadow of node features (vectorized) + zero stats3/pooled3
// ------------------------------------------------------------------
__global__ __launch_bounds__(256) void k_cvt(const float* __restrict__ x,
                                             bf16* __restrict__ xh,
                                             float* __restrict__ zbuf)
{
    int i = blockIdx.x*256 + threadIdx.x;   // 8192 blocks -> NN*64/4 threads
    float4 v = ((const float4*)x)[i];
    short4 o;
    o.x = f2bf_s(v.x); o.y = f2bf_s(v.y);
    o.z = f2bf_s(v.z); o.w = f2bf_s(v.w);
    ((short4*)xh)[i] = o;
    if (i < 3*128 + 3*BG*64) zbuf[i] = 0.f;
}

// ------------------------------------------------------------------
// Weight prep (once/launch): Wt[n][k] = W[k][n], split bf16 hi/lo.
// ------------------------------------------------------------------
__global__ __launch_bounds__(256) void k_wprep(
    const float* __restrict__ gw1, const float* __restrict__ gw2,
    const float* __restrict__ iw,
    short* __restrict__ w1h, short* __restrict__ w1l,
    short* __restrict__ w2h, short* __restrict__ w2l,
    short* __restrict__ wih, short* __restrict__ wil)
{
    int i = blockIdx.x*256 + threadIdx.x;
    if (i >= 3*LAYERS*4096) return;
    int msel = i / (LAYERS*4096);
    int rem  = i % (LAYERS*4096);
    int l = rem >> 12, idx = rem & 4095;
    int n = idx >> 6, k = idx & 63;
    const float* src = (msel==0) ? gw1 : (msel==1) ? gw2 : iw;
    float v = src[l*4096 + k*64 + n];
    short hi = f2bf_s(v);
    short lo = f2bf_s(v - bf2f_s(hi));
    short* dh = (msel==0) ? w1h : (msel==1) ? w2h : wih;
    short* dl = (msel==0) ? w1l : (msel==1) ? w2l : wil;
    dh[rem] = hi;
    dl[rem] = lo;
}

// ------------------------------------------------------------------
// FUSED aggregate + GIN MLP (+ folded outer MLP of previous layer on
// blocks 0-255 when pooled_prev != nullptr).
// r0 structure; gather inner loop deepened to 8 edges/iter with 8
// independent accumulator quads (2x memory-level parallelism).
// ------------------------------------------------------------------
__global__ __launch_bounds__(256) void k_agg_gin(
    const bf16* __restrict__ xh,
    const int* __restrict__ rowptr, const int* __restrict__ col,
    const float* __restrict__ epsp,
    const short* __restrict__ w1h, const short* __restrict__ w1l,
    const float* __restrict__ b1,
    const short* __restrict__ w2h, const short* __restrict__ w2l,
    const float* __restrict__ b2,
    float* __restrict__ big, float* __restrict__ stats,
    const float* __restrict__ pooled_prev, const float* __restrict__ owp,
    const float* __restrict__ obp, float* __restrict__ feats, int coffp)
{
    __shared__ __align__(16) char buf[4][9472];
    __shared__ float red[2][4][64];
    int tid = threadIdx.x, wv = tid >> 6, lane = tid & 63;
    int q = lane >> 4, m = lane & 15;
    int nb = blockIdx.x*128 + wv*32;
    short* Sh = (short*)buf[wv];
    short* Sl = Sh + 2304;      // 32*72
    float ep = 1.0f + *epsp;

    // folded outer MLP of previous layer
    if (pooled_prev && blockIdx.x < 256) {
        int g = blockIdx.x*256 + tid;
        int bb = g >> 6, j = g & 63;
        const float* pr = pooled_prev + bb*64;
        float a = obp[j];
        for (int k = 0; k < 64; k++) a = fmaf(pr[k], owp[k*64 + j], a);
        feats[bb*192 + coffp + j] = fmaxf(a, 0.f);
    }

    // ---- Phase 1: group-per-node gather ----
    int gv = rowptr[nb + (lane < 33 ? lane : 32)];
    int fo = m * 4;              // ushort feature offset (8 B per lane)
    const unsigned short* xt = (const unsigned short*)xh;

    for (int i = 0; i < 8; i++) {
        int row = i*4 + q;
        int rs = __shfl(gv, row, 64);
        int re = __shfl(gv, row+1, 64);
        float a0=0.f,a1=0.f,a2=0.f,a3=0.f;
        float e0=0.f,e1=0.f,e2=0.f,e3=0.f;
        float g0=0.f,g1=0.f,g2=0.f,g3=0.f;
        float h0=0.f,h1=0.f,h2=0.f,h3=0.f;
        float p0=0.f,p1=0.f,p2=0.f,p3=0.f;
        float u0=0.f,u1=0.f,u2=0.f,u3=0.f;
        float v0=0.f,v1=0.f,v2=0.f,v3=0.f;
        float w0=0.f,w1=0.f,w2=0.f,w3=0.f;
        int r = rs;
        // 8 edges/iter, 8 independent accumulator quads
        for (; r + 8 <= re; r += 8) {
            int ca = col[r],   cb = col[r+1], cc = col[r+2], cd = col[r+3];
            int ce = col[r+4], cf = col[r+5], cg = col[r+6], ch = col[r+7];
            acc4(xt + (((size_t)ca) << 6) + fo, a0,a1,a2,a3);
            acc4(xt + (((size_t)cb) << 6) + fo, e0,e1,e2,e3);
            acc4(xt + (((size_t)cc) << 6) + fo, g0,g1,g2,g3);
            acc4(xt + (((size_t)cd) << 6) + fo, h0,h1,h2,h3);
            acc4(xt + (((size_t)ce) << 6) + fo, p0,p1,p2,p3);
            acc4(xt + (((size_t)cf) << 6) + fo, u0,u1,u2,u3);
            acc4(xt + (((size_t)cg) << 6) + fo, v0,v1,v2,v3);
            acc4(xt + (((size_t)ch) << 6) + fo, w0,w1,w2,w3);
        }
        if (r + 4 <= re) {
            int ca = col[r], cb = col[r+1], cc = col[r+2], cd = col[r+3];
            acc4(xt + (((size_t)ca) << 6) + fo, a0,a1,a2,a3);
            acc4(xt + (((size_t)cb) << 6) + fo, e0,e1,e2,e3);
            acc4(xt + (((size_t)cc) << 6) + fo, g0,g1,g2,g3);
            acc4(xt + (((size_t)cd) << 6) + fo, h0,h1,h2,h3);
            r += 4;
        }
        for (; r < re; r++)
            acc4(xt + (((size_t)col[r]) << 6) + fo, a0,a1,a2,a3);
        a0 += e0 + g0 + h0 + p0 + u0 + v0 + w0;
        a1 += e1 + g1 + h1 + p1 + u1 + v1 + w1;
        a2 += e2 + g2 + h2 + p2 + u2 + v2 + w2;
        a3 += e3 + g3 + h3 + p3 + u3 + v3 + w3;
        ushort4 sv = *(const ushort4*)(xt + (((size_t)(nb+row)) << 6) + fo);
        a0 = fmaf(ep, bf2f_s((short)sv.x), a0);
        a1 = fmaf(ep, bf2f_s((short)sv.y), a1);
        a2 = fmaf(ep, bf2f_s((short)sv.z), a2);
        a3 = fmaf(ep, bf2f_s((short)sv.w), a3);
        short4 hh, ll;
        hh.x = f2bf_s(a0); ll.x = f2bf_s(a0 - bf2f_s(hh.x));
        hh.y = f2bf_s(a1); ll.y = f2bf_s(a1 - bf2f_s(hh.y));
        hh.z = f2bf_s(a2); ll.z = f2bf_s(a2 - bf2f_s(hh.z));
        hh.w = f2bf_s(a3); ll.w = f2bf_s(a3 - bf2f_s(hh.w));
        *(short4*)(Sh + row*72 + fo) = hh;
        *(short4*)(Sl + row*72 + fo) = ll;
    }
    __syncthreads();

    // ---- Phase 2: GEMM1 (A from LDS) ----
    short8 Ah[2][2], Al[2][2];
    #pragma unroll
    for (int mc=0; mc<2; mc++)
      #pragma unroll
      for (int kc=0; kc<2; kc++){
        Ah[mc][kc] = *(const short8*)(Sh + (mc*16+m)*72 + kc*32 + q*8);
        Al[mc][kc] = *(const short8*)(Sl + (mc*16+m)*72 + kc*32 + q*8);
      }
    floatx4 acc[2][4];
    #pragma unroll
    for (int mc=0;mc<2;mc++)
      #pragma unroll
      for (int nc=0;nc<4;nc++) acc[mc][nc] = (floatx4){0.f,0.f,0.f,0.f};
    #pragma unroll
    for (int nc=0;nc<4;nc++){
      #pragma unroll
      for (int kc=0;kc<2;kc++){
        short8 bh = *(const short8*)(w1h + (nc*16+m)*64 + kc*32 + q*8);
        short8 bl = *(const short8*)(w1l + (nc*16+m)*64 + kc*32 + q*8);
        #pragma unroll
        for (int mc=0;mc<2;mc++){
          acc[mc][nc] = __builtin_amdgcn_mfma_f32_16x16x32_bf16(Ah[mc][kc], bh, acc[mc][nc],0,0,0);
          acc[mc][nc] = __builtin_amdgcn_mfma_f32_16x16x32_bf16(Al[mc][kc], bh, acc[mc][nc],0,0,0);
          acc[mc][nc] = __builtin_amdgcn_mfma_f32_16x16x32_bf16(Ah[mc][kc], bl, acc[mc][nc],0,0,0);
        }
      }
    }

    // epilogue 1: bias + relu, split back into LDS
    #pragma unroll
    for (int nc=0;nc<4;nc++){
      float bia = b1[nc*16+m];
      #pragma unroll
      for (int mc=0;mc<2;mc++)
        #pragma unroll
        for (int r=0;r<4;r++){
          float v = fmaxf(acc[mc][nc][r] + bia, 0.f);
          int row = mc*16 + q*4 + r, cl = nc*16 + m;
          short hb = f2bf_s(v);
          Sh[row*72+cl] = hb;
          Sl[row*72+cl] = f2bf_s(v - bf2f_s(hb));
        }
    }
    __syncthreads();

    // GEMM2
    short8 A2h[2][2], A2l[2][2];
    #pragma unroll
    for (int mc=0; mc<2; mc++)
      #pragma unroll
      for (int kc=0; kc<2; kc++){
        A2h[mc][kc] = *(const short8*)(Sh + (mc*16+m)*72 + kc*32 + q*8);
        A2l[mc][kc] = *(const short8*)(Sl + (mc*16+m)*72 + kc*32 + q*8);
      }
    floatx4 acc2[2][4];
    #pragma unroll
    for (int mc=0;mc<2;mc++)
      #pragma unroll
      for (int nc=0;nc<4;nc++) acc2[mc][nc] = (floatx4){0.f,0.f,0.f,0.f};
    #pragma unroll
    for (int nc=0;nc<4;nc++){
      #pragma unroll
      for (int kc=0;kc<2;kc++){
        short8 bh = *(const short8*)(w2h + (nc*16+m)*64 + kc*32 + q*8);
        short8 bl = *(const short8*)(w2l + (nc*16+m)*64 + kc*32 + q*8);
        #pragma unroll
        for (int mc=0;mc<2;mc++){
          acc2[mc][nc] = __builtin_amdgcn_mfma_f32_16x16x32_bf16(A2h[mc][kc], bh, acc2[mc][nc],0,0,0);
          acc2[mc][nc] = __builtin_amdgcn_mfma_f32_16x16x32_bf16(A2l[mc][kc], bh, acc2[mc][nc],0,0,0);
          acc2[mc][nc] = __builtin_amdgcn_mfma_f32_16x16x32_bf16(A2h[mc][kc], bl, acc2[mc][nc],0,0,0);
        }
      }
    }

    // epilogue 2: bias, store h2, BN stats
    #pragma unroll
    for (int nc=0;nc<4;nc++){
      float bia = b2[nc*16+m];
      float s = 0.f, s2 = 0.f;
      #pragma unroll
      for (int mc=0;mc<2;mc++)
        #pragma unroll
        for (int r=0;r<4;r++){
          float v = acc2[mc][nc][r] + bia;
          big[(((size_t)(nb + mc*16 + q*4 + r)) << 6) + nc*16 + m] = v;
          s += v; s2 = fmaf(v, v, s2);
        }
      s  += __shfl_xor(s, 16, 64);  s  += __shfl_xor(s, 32, 64);
      s2 += __shfl_xor(s2,16, 64);  s2 += __shfl_xor(s2,32, 64);
      if (q == 0){ red[0][wv][nc*16+m] = s; red[1][wv][nc*16+m] = s2; }
    }
    __syncthreads();
    if (tid < 128){
      int which = tid >> 6, c = tid & 63;
      float a = red[which][0][c]+red[which][1][c]+red[which][2][c]+red[which][3][c];
      unsafeAtomicAdd(stats + which*64 + c, a);
    }
}

// ------------------------------------------------------------------
// MFMA BN-apply (params inline from stats) + inner MLP + fused pool.
// ------------------------------------------------------------------
__global__ __launch_bounds__(256) void k_bn_inner(
    const float* __restrict__ big, const float* __restrict__ stats,
    const float* __restrict__ gam, const float* __restrict__ bet,
    const short* __restrict__ wih, const short* __restrict__ wil,
    const float* __restrict__ bi,
    bf16* __restrict__ xh,
    const int* __restrict__ gidx, float* __restrict__ pooled)
{
    __shared__ __align__(16) char buf[4][9472];
    int tid = threadIdx.x, wv = tid >> 6, lane = tid & 63;
    int q = lane >> 4, m = lane & 15;
    int nb = blockIdx.x*128 + wv*32;
    short* Sh = (short*)buf[wv];
    short* Sl = Sh + 2304;

    // BN params inline (stats complete: previous dispatch)
    float mu  = stats[lane]    * (1.0f/NN);
    float ex2 = stats[64+lane] * (1.0f/NN);
    float var = ex2 - mu*mu;
    float sc  = gam[lane] * rsqrtf(var + 1e-5f);
    float sh  = bet[lane] - mu*sc;

    for (int rr = 0; rr < 32; rr++){
        float v = big[(((size_t)(nb+rr)) << 6) + lane];
        v = fmaxf(fmaf(v, sc, sh), 0.f);
        xh[(((size_t)(nb+rr)) << 6) + lane] = __float2bfloat16(v);
        short hb = f2bf_s(v);
        Sh[rr*72 + lane] = hb;
        Sl[rr*72 + lane] = f2bf_s(v - bf2f_s(hb));
    }
    __syncthreads();

    short8 A2h[2][2], A2l[2][2];
    #pragma unroll
    for (int mc=0; mc<2; mc++)
      #pragma unroll
      for (int kc=0; kc<2; kc++){
        A2h[mc][kc] = *(const short8*)(Sh + (mc*16+m)*72 + kc*32 + q*8);
        A2l[mc][kc] = *(const short8*)(Sl + (mc*16+m)*72 + kc*32 + q*8);
      }
    floatx4 acc[2][4];
    #pragma unroll
    for (int mc=0;mc<2;mc++)
      #pragma unroll
      for (int nc=0;nc<4;nc++) acc[mc][nc] = (floatx4){0.f,0.f,0.f,0.f};
    #pragma unroll
    for (int nc=0;nc<4;nc++){
      #pragma unroll
      for (int kc=0;kc<2;kc++){
        short8 bh = *(const short8*)(wih + (nc*16+m)*64 + kc*32 + q*8);
        short8 bl = *(const short8*)(wil + (nc*16+m)*64 + kc*32 + q*8);
        #pragma unroll
        for (int mc=0;mc<2;mc++){
          acc[mc][nc] = __builtin_amdgcn_mfma_f32_16x16x32_bf16(A2h[mc][kc], bh, acc[mc][nc],0,0,0);
          acc[mc][nc] = __builtin_amdgcn_mfma_f32_16x16x32_bf16(A2l[mc][kc], bh, acc[mc][nc],0,0,0);
          acc[mc][nc] = __builtin_amdgcn_mfma_f32_16x16x32_bf16(A2h[mc][kc], bl, acc[mc][nc],0,0,0);
        }
      }
    }
    __syncthreads();   // LDS reads done; safe to repurpose buf

    float* P = (float*)buf[wv];
    #pragma unroll
    for (int nc=0;nc<4;nc++){
      float bia = bi[nc*16+m];
      #pragma unroll
      for (int mc=0;mc<2;mc++)
        #pragma unroll
        for (int r=0;r<4;r++){
          float v = fmaxf(acc[mc][nc][r] + bia, 0.f);
          P[(mc*16 + q*4 + r)*66 + nc*16 + m] = v;
        }
    }
    __syncthreads();

    int gv = (lane < 32) ? gidx[nb + lane] : 0;
    int cur = __shfl(gv, 0, 64);
    float a = 0.f;
    for (int rr = 0; rr < 32; rr++){
        int g = __shfl(gv, rr, 64);
        if (g != cur){
            unsafeAtomicAdd(pooled + (size_t)cur*64 + lane, a);
            a = 0.f; cur = g;
        }
        a += P[rr*66 + lane];
    }
    unsafeAtomicAdd(pooled + (size_t)cur*64 + lane, a);
}

// ------------------------------------------------------------------
// Tail: TG graphs per block; corpus layer-2 outer computed inline.
// ------------------------------------------------------------------
__global__ __launch_bounds__(256) void k_tail(
    const float* __restrict__ qf, const float* __restrict__ cf,
    const float* __restrict__ pooled_c2,
    const float* __restrict__ ow2, const float* __restrict__ ob2,
    const float* __restrict__ cw1, const float* __restrict__ cb1,
    const float* __restrict__ cw2, const float* __restrict__ cb2,
    const float* __restrict__ sw1, const float* __restrict__ sb1,
    const float* __restrict__ sw2, const float* __restrict__ sb2,
    const float* __restrict__ nw,  const float* __restrict__ nwb,
    const float* __restrict__ nb,
    const float* __restrict__ mw1, const float* __restrict__ mb1,
    const float* __restrict__ mw2, const float* __restrict__ mb2,
    const float* __restrict__ alpha, const float* __restrict__ beta,
    float* __restrict__ out)
{
    __shared__ float cws[192*96];
    __shared__ float diff[TG][192];
    __shared__ float e1s[TG][64], e2s[TG][64];
    __shared__ float h1s[TG][96], h2s[TG][96];
    __shared__ float s1s[TG][16], s2s[TG][16], srep[TG][16];
    __shared__ float red[16][16][TG];

    int t = threadIdx.x;
    int b0 = blockIdx.x * TG;

    // inline corpus outer (layer 2): e2s = relu(pooled_c2 @ ow2 + ob2)
    {
        int b = t >> 5, o = (t & 31) * 2;
        const float* pr = pooled_c2 + (size_t)(b0 + b)*64;
        float a0 = ob2[o], a1 = ob2[o+1];
        for (int k = 0; k < 64; k++) {
            float p = pr[k];
            a0 = fmaf(p, ow2[k*64 + o], a0);
            a1 = fmaf(p, ow2[k*64 + o + 1], a1);
        }
        e2s[b][o]   = fmaxf(a0, 0.f);
        e2s[b][o+1] = fmaxf(a1, 0.f);
    }
    for (int i = t; i < 192*96; i += 256) cws[i] = cw1[i];
    __syncthreads();

    for (int i = t; i < TG*192; i += 256) {
        int b = i / 192, f = i % 192;
        float qv = qf[(b0+b)*192 + f];
        float cv = (f < 128) ? cf[(b0+b)*192 + f] : e2s[b][f-128];
        float d = qv - cv;
        diff[b][f] = __expf(-d*d);
        if (f >= 128) e1s[b][f-128] = qv;
    }
    __syncthreads();

    {
        int b = t >> 5, o = (t & 31) * 3;
        float a0 = cb1[o], a1 = cb1[o+1], a2 = cb1[o+2];
        for (int f = 0; f < 192; f++) {
            float d = diff[b][f];
            const float* w = cws + f*96 + o;
            a0 = fmaf(d, w[0], a0);
            a1 = fmaf(d, w[1], a1);
            a2 = fmaf(d, w[2], a2);
        }
        h1s[b][o] = fmaxf(a0, 0.f);
        h1s[b][o+1] = fmaxf(a1, 0.f);
        h1s[b][o+2] = fmaxf(a2, 0.f);
    }
    __syncthreads();
    for (int i = t; i < 96*96; i += 256) cws[i] = cw2[i];
    __syncthreads();
    {
        int b = t >> 5, o = (t & 31) * 3;
        float a0 = cb2[o], a1 = cb2[o+1], a2 = cb2[o+2];
        for (int f = 0; f < 96; f++) {
            float d = h1s[b][f];
            const float* w = cws + f*96 + o;
            a0 = fmaf(d, w[0], a0);
            a1 = fmaf(d, w[1], a1);
            a2 = fmaf(d, w[2], a2);
        }
        h2s[b][o] = tanhf(a0);
        h2s[b][o+1] = tanhf(a1);
        h2s[b][o+2] = tanhf(a2);
    }
    __syncthreads();
    if (t < TG*16) {
        int b = t >> 4, o = t & 15;
        float a = sb1[o];
        for (int f = 0; f < 96; f++) a = fmaf(h2s[b][f], sw1[f*16+o], a);
        s1s[b][o] = fmaxf(a, 0.f);
    }

    {
        int tt = t & 15, gq = t >> 4;
        int g0 = gq * 4;
        int lane = t & 63;
        float e1v[TG];
        #pragma unroll
        for (int b = 0; b < TG; b++) e1v[b] = e1s[b][lane];
        float v0[TG], v1[TG], v2[TG], v3[TG];
        #pragma unroll
        for (int b = 0; b < TG; b++) { v0[b]=0.f; v1[b]=0.f; v2[b]=0.f; v3[b]=0.f; }
        for (int f = 0; f < 64; f++) {
            const float* wp = nw + ((size_t)f*64 + g0)*16 + tt;
            float w0 = wp[0], w1 = wp[16], w2 = wp[32], w3 = wp[48];
            #pragma unroll
            for (int b = 0; b < TG; b++) {
                float e = __shfl(e1v[b], f, 64);
                v0[b] = fmaf(e, w0, v0[b]);
                v1[b] = fmaf(e, w1, v1[b]);
                v2[b] = fmaf(e, w2, v2[b]);
                v3[b] = fmaf(e, w3, v3[b]);
            }
        }
        #pragma unroll
        for (int b = 0; b < TG; b++) {
            float p = v0[b]*e2s[b][g0] + v1[b]*e2s[b][g0+1]
                    + v2[b]*e2s[b][g0+2] + v3[b]*e2s[b][g0+3];
            red[gq][tt][b] = p;
        }
    }
    __syncthreads();
    if (t < TG*16) {
        int b = t >> 4, tt = t & 15;
        float scv = 0.f;
        #pragma unroll
        for (int gq = 0; gq < 16; gq++) scv += red[gq][tt][b];
        float blk = nb[tt];
        for (int f = 0; f < 64; f++) blk = fmaf(e1s[b][f], nwb[tt*128 + f], blk);
        for (int f = 0; f < 64; f++) blk = fmaf(e2s[b][f], nwb[tt*128 + 64 + f], blk);
        srep[b][tt] = fmaxf(scv + blk, 0.f);
    }
    __syncthreads();
    if (t < TG*16) {
        int b = t >> 4, o = t & 15;
        float a = mb1[o];
        #pragma unroll
        for (int f = 0; f < 16; f++) a = fmaf(srep[b][f], mw1[f*16+o], a);
        s2s[b][o] = fmaxf(a, 0.f);
    }
    __syncthreads();
    if (t < TG) {
        float sco = sb2[0], sm = mb2[0];
        #pragma unroll
        for (int f = 0; f < 16; f++) {
            sco = fmaf(s1s[t][f], sw2[f], sco);
            sm  = fmaf(s2s[t][f], mw2[f], sm);
        }
        float score = 1.f / (1.f + __expf(-sco));
        float sim   = 1.f / (1.f + __expf(-sm));
        out[b0 + t] = alpha[0]*score + beta[0]*sim;
    }
}

// ------------------------------------------------------------------
extern "C" void kernel_launch(void* const* d_in, const int* in_sizes, int n_in,
                              void* d_out, int out_size, void* d_ws, size_t ws_size,
                              hipStream_t stream)
{
    const float* qx  = (const float*)d_in[0];
    const float* cx  = (const float*)d_in[1];
    const int*   qei = (const int*)d_in[2];
    const int*   cei = (const int*)d_in[3];
    const int*   qgi = (const int*)d_in[4];
    const int*   cgi = (const int*)d_in[5];
    const float* Wgw1 = (const float*)d_in[6];
    const float* Wgb1 = (const float*)d_in[7];
    const float* Wgw2 = (const float*)d_in[8];
    const float* Wgb2 = (const float*)d_in[9];
    const float* Wgam = (const float*)d_in[10];
    const float* Wbet = (const float*)d_in[11];
    const float* Weps = (const float*)d_in[12];
    const float* Wiw  = (const float*)d_in[13];
    const float* Wib  = (const float*)d_in[14];
    const float* Wow  = (const float*)d_in[15];
    const float* Wob  = (const float*)d_in[16];
    const float* Wcw1 = (const float*)d_in[17];
    const float* Wcb1 = (const float*)d_in[18];
    const float* Wcw2 = (const float*)d_in[19];
    const float* Wcb2 = (const float*)d_in[20];
    const float* Wsw1 = (const float*)d_in[21];
    const float* Wsb1 = (const float*)d_in[22];
    const float* Wsw2 = (const float*)d_in[23];
    const float* Wsb2 = (const float*)d_in[24];
    const float* Wnw  = (const float*)d_in[25];
    const float* Wnwb = (const float*)d_in[26];
    const float* Wnb  = (const float*)d_in[27];
    const float* Wmw1 = (const float*)d_in[28];
    const float* Wmb1 = (const float*)d_in[29];
    const float* Wmw2 = (const float*)d_in[30];
    const float* Wmb2 = (const float*)d_in[31];
    const float* Wal  = (const float*)d_in[32];
    const float* Wbe  = (const float*)d_in[33];

    float* F      = (float*)d_ws;
    float* big    = F;                        // N*64 (h2; rank aliases)
    float* zbuf   = F + 8388608;              // stats3(384) + pooled3(196608)
    float* stats3 = zbuf;
    float* pooled3= zbuf + 384;
    float* qf     = pooled3 + 3*BG*64;        // BG*192
    float* cf     = qf + 196608;              // BG*192
    int*   rowptr = (int*)(cf + 196608);      // NN+1
    int*   cnt    = rowptr + (NN + 1);        // NN (histogram)
    int*   col    = cnt + NN;                 // NEDGE
    int*   bsum   = col + NEDGE;              // 128
    int*   boff   = bsum + 128;               // 128
    bf16*  xh     = (bf16*)(boff + 128);      // N*64 bf16
    int*   rank   = (int*)big;                // NEDGE (dead during CSR build)
    uintptr_t wtb = (uintptr_t)(xh + (size_t)NN*64);
    wtb = (wtb + 63) & ~((uintptr_t)63);
    short* w1h = (short*)wtb;                 // 3*4096 each
    short* w1l = w1h + 3*4096;
    short* w2h = w1l + 3*4096;
    short* w2l = w2h + 3*4096;
    short* wih = w2l + 3*4096;
    short* wil = wih + 3*4096;

    k_wprep<<<144, 256, 0, stream>>>(Wgw1, Wgw2, Wiw, w1h, w1l, w2h, w2l, wih, wil);

    for (int side = 0; side < 2; side++) {
        const float* x0 = side ? cx  : qx;
        const int* ei   = side ? cei : qei;
        const int* gi   = side ? cgi : qgi;
        float* feats    = side ? cf  : qf;

        // side 1's k_zero also performs outer(l=2) for side 0 (qf cols 128..191)
        if (side == 0)
            k_zero<<<NN/256, 256, 0, stream>>>(cnt, nullptr, nullptr, nullptr, nullptr);
        else
            k_zero<<<NN/256, 256, 0, stream>>>(cnt, pooled3 + 2*BG*64,
                                               Wow + 2*4096, Wob + 2*64, qf);
        k_hist<<<NEDGE/256, 256, 0, stream>>>(ei, cnt, rank);
        k_scan1<<<128, 256, 0, stream>>>(cnt, rowptr, bsum);
        k_scan2<<<1, 128, 0, stream>>>(bsum, boff, rowptr);
        k_scan3<<<NN/256, 256, 0, stream>>>(rowptr, boff);
        k_fill<<<NEDGE/256, 256, 0, stream>>>(ei, rowptr, rank, col);

        k_cvt<<<NN*64/1024, 256, 0, stream>>>(x0, xh, zbuf);

        for (int l = 0; l < LAYERS; l++) {
            const float* pprev = (l == 0) ? nullptr : pooled3 + (size_t)(l-1)*BG*64;
            const float* owp   = (l == 0) ? nullptr : Wow + (l-1)*4096;
            const float* obp   = (l == 0) ? nullptr : Wob + (l-1)*64;
            k_agg_gin<<<NN/128, 256, 0, stream>>>(xh, rowptr, col, Weps + l,
                                                  w1h + l*4096, w1l + l*4096, Wgb1 + l*64,
                                                  w2h + l*4096, w2l + l*4096, Wgb2 + l*64,
                                                  big, stats3 + l*128,
                                                  pprev, owp, obp, feats, (l-1)*64);
            k_bn_inner<<<NN/128, 256, 0, stream>>>(big, stats3 + l*128,
                                                   Wgam + l*64, Wbet + l*64,
                                                   wih + l*4096, wil + l*4096,
                                                   Wib + l*64, xh, gi,
                                                   pooled3 + (size_t)l*BG*64);
        }
    }

    k_tail<<<BG/TG, 256, 0, stream>>>(qf, cf, pooled3 + 2*BG*64,
                                      Wow + 2*4096, Wob + 2*64,
                                      Wcw1, Wcb1, Wcw2, Wcb2,
                                      Wsw1, Wsb1, Wsw2, Wsb2,
                                      Wnw, Wnwb, Wnb, Wmw1, Wmb1, Wmw2, Wmb2,
                                      Wal, Wbe, (float*)d_out);
}

// Round 6
// 908.368 us; speedup vs baseline: 1.2321x; 1.1880x over previous
//
#include <hip/hip_runtime.h>
#include <hip/hip_bf16.h>

typedef __hip_bfloat16 bf16;
typedef __attribute__((ext_vector_type(8))) short short8;
typedef __attribute__((ext_vector_type(4))) float floatx4;

#define NN     131072
#define NEDGE  1048576
#define BG     1024
#define LAYERS 3
#define TG     8      // graphs per tail block

// bf16 split helpers (RNE)
__device__ __forceinline__ short f2bf_s(float f){
    union { float f; unsigned u; } x; x.f = f;
    unsigned r = x.u + 0x7fffu + ((x.u >> 16) & 1u);
    return (short)(r >> 16);
}
__device__ __forceinline__ float bf2f_s(short s){
    union { unsigned u; float f; } x; x.u = ((unsigned)(unsigned short)s) << 16;
    return x.f;
}
__device__ __forceinline__ void acc4(const unsigned short* p,
                                     float& a0, float& a1, float& a2, float& a3){
    ushort4 u = *(const ushort4*)p;
    a0 += bf2f_s((short)u.x); a1 += bf2f_s((short)u.y);
    a2 += bf2f_s((short)u.z); a3 += bf2f_s((short)u.w);
}

// ------------------------------------------------------------------
// CSR build (deterministic fill via rank captured in k_hist).
// k_zero also carries the folded outer MLP of the PREVIOUS side's
// last layer (pooled_prev != nullptr on side 1 only).
// ------------------------------------------------------------------
__global__ __launch_bounds__(256) void k_zero(int* __restrict__ cnt,
    const float* __restrict__ pooled_prev, const float* __restrict__ owp,
    const float* __restrict__ obp, float* __restrict__ feats_prev)
{
    int i = blockIdx.x*256 + threadIdx.x;
    if (i < NN) cnt[i] = 0;
    if (pooled_prev && blockIdx.x < 256) {
        int bb = i >> 6, j = i & 63;
        const float* pr = pooled_prev + bb*64;
        float a = obp[j];
        for (int k = 0; k < 64; k++) a = fmaf(pr[k], owp[k*64 + j], a);
        feats_prev[bb*192 + 128 + j] = fmaxf(a, 0.f);
    }
}

__global__ __launch_bounds__(256) void k_hist(const int* __restrict__ ei,
                                              int* __restrict__ cnt,
                                              int* __restrict__ rank)
{
    int e = blockIdx.x*256 + threadIdx.x;
    rank[e] = atomicAdd(cnt + ei[NEDGE + e], 1);
}

__global__ __launch_bounds__(256) void k_scan1(const int* __restrict__ cnt,
    int* __restrict__ rowptr, int* __restrict__ bsum)
{
    __shared__ int sd[256];
    int t = threadIdx.x;
    int base = blockIdx.x*1024 + t*4;
    int c0 = cnt[base], c1 = cnt[base+1], c2 = cnt[base+2], c3 = cnt[base+3];
    int tsum = c0 + c1 + c2 + c3;
    sd[t] = tsum;
    __syncthreads();
    for (int off = 1; off < 256; off <<= 1) {
        int v = (t >= off) ? sd[t-off] : 0;
        __syncthreads();
        sd[t] += v;
        __syncthreads();
    }
    int excl = sd[t] - tsum;
    rowptr[base]   = excl;
    rowptr[base+1] = excl + c0;
    rowptr[base+2] = excl + c0 + c1;
    rowptr[base+3] = excl + c0 + c1 + c2;
    if (t == 255) bsum[blockIdx.x] = sd[255];
}

__global__ __launch_bounds__(128) void k_scan2(const int* __restrict__ bsum,
    int* __restrict__ boff, int* __restrict__ rowptr)
{
    __shared__ int sd[128];
    int t = threadIdx.x;
    int v0 = bsum[t];
    sd[t] = v0;
    __syncthreads();
    for (int off = 1; off < 128; off <<= 1) {
        int v = (t >= off) ? sd[t-off] : 0;
        __syncthreads();
        sd[t] += v;
        __syncthreads();
    }
    boff[t] = sd[t] - v0;
    if (t == 0) rowptr[NN] = NEDGE;
}

__global__ __launch_bounds__(256) void k_scan3(int* __restrict__ rowptr,
    const int* __restrict__ boff)
{
    int i = blockIdx.x*256 + threadIdx.x;
    rowptr[i] += boff[i >> 10];
}

__global__ __launch_bounds__(256) void k_fill(const int* __restrict__ ei,
    const int* __restrict__ rowptr, const int* __restrict__ rank,
    int* __restrict__ col)
{
    int e = blockIdx.x*256 + threadIdx.x;
    int s = ei[e];
    int d = ei[NEDGE + e];
    col[rowptr[d] + rank[e]] = s;
}

// ------------------------------------------------------------------
// fp32 -> bf16 shadow of node features (vectorized) + zero stats3/pooled3
// ------------------------------------------------------------------
__global__ __launch_bounds__(256) void k_cvt(const float* __restrict__ x,
                                             bf16* __restrict__ xh,
                                             float* __restrict__ zbuf)
{
    int i = blockIdx.x*256 + threadIdx.x;   // 8192 blocks -> NN*64/4 threads
    float4 v = ((const float4*)x)[i];
    short4 o;
    o.x = f2bf_s(v.x); o.y = f2bf_s(v.y);
    o.z = f2bf_s(v.z); o.w = f2bf_s(v.w);
    ((short4*)xh)[i] = o;
    if (i < 3*128 + 3*BG*64) zbuf[i] = 0.f;
}

// ------------------------------------------------------------------
// Weight prep (once/launch): Wt[n][k] = W[k][n], split bf16 hi/lo.
// ------------------------------------------------------------------
__global__ __launch_bounds__(256) void k_wprep(
    const float* __restrict__ gw1, const float* __restrict__ gw2,
    const float* __restrict__ iw,
    short* __restrict__ w1h, short* __restrict__ w1l,
    short* __restrict__ w2h, short* __restrict__ w2l,
    short* __restrict__ wih, short* __restrict__ wil)
{
    int i = blockIdx.x*256 + threadIdx.x;
    if (i >= 3*LAYERS*4096) return;
    int msel = i / (LAYERS*4096);
    int rem  = i % (LAYERS*4096);
    int l = rem >> 12, idx = rem & 4095;
    int n = idx >> 6, k = idx & 63;
    const float* src = (msel==0) ? gw1 : (msel==1) ? gw2 : iw;
    float v = src[l*4096 + k*64 + n];
    short hi = f2bf_s(v);
    short lo = f2bf_s(v - bf2f_s(hi));
    short* dh = (msel==0) ? w1h : (msel==1) ? w2h : wih;
    short* dl = (msel==0) ? w1l : (msel==1) ? w2l : wil;
    dh[rem] = hi;
    dl[rem] = lo;
}

// ------------------------------------------------------------------
// FUSED aggregate + GIN MLP (+ folded outer MLP of previous layer on
// blocks 0-255 when pooled_prev != nullptr).
// r0-exact structure; ONLY change vs r0: h2 intermediate (big) is
// stored as bf16 (halves the write; BN stats remain fp32-exact).
// ------------------------------------------------------------------
__global__ __launch_bounds__(256) void k_agg_gin(
    const bf16* __restrict__ xh,
    const int* __restrict__ rowptr, const int* __restrict__ col,
    const float* __restrict__ epsp,
    const short* __restrict__ w1h, const short* __restrict__ w1l,
    const float* __restrict__ b1,
    const short* __restrict__ w2h, const short* __restrict__ w2l,
    const float* __restrict__ b2,
    unsigned short* __restrict__ bigh, float* __restrict__ stats,
    const float* __restrict__ pooled_prev, const float* __restrict__ owp,
    const float* __restrict__ obp, float* __restrict__ feats, int coffp)
{
    __shared__ __align__(16) char buf[4][9472];
    __shared__ float red[2][4][64];
    int tid = threadIdx.x, wv = tid >> 6, lane = tid & 63;
    int q = lane >> 4, m = lane & 15;
    int nb = blockIdx.x*128 + wv*32;
    short* Sh = (short*)buf[wv];
    short* Sl = Sh + 2304;      // 32*72
    float ep = 1.0f + *epsp;

    // folded outer MLP of previous layer
    if (pooled_prev && blockIdx.x < 256) {
        int g = blockIdx.x*256 + tid;
        int bb = g >> 6, j = g & 63;
        const float* pr = pooled_prev + bb*64;
        float a = obp[j];
        for (int k = 0; k < 64; k++) a = fmaf(pr[k], owp[k*64 + j], a);
        feats[bb*192 + coffp + j] = fmaxf(a, 0.f);
    }

    // ---- Phase 1: group-per-node gather ----
    int gv = rowptr[nb + (lane < 33 ? lane : 32)];
    int fo = m * 4;              // ushort feature offset (8 B per lane)
    const unsigned short* xt = (const unsigned short*)xh;

    for (int i = 0; i < 8; i++) {
        int row = i*4 + q;
        int rs = __shfl(gv, row, 64);
        int re = __shfl(gv, row+1, 64);
        float a0=0.f,a1=0.f,a2=0.f,a3=0.f;
        float e0=0.f,e1=0.f,e2=0.f,e3=0.f;
        float g0=0.f,g1=0.f,g2=0.f,g3=0.f;
        float h0=0.f,h1=0.f,h2=0.f,h3=0.f;
        int r = rs;
        for (; r + 4 <= re; r += 4) {
            int ca = col[r], cb = col[r+1], cc = col[r+2], cd = col[r+3];
            acc4(xt + (((size_t)ca) << 6) + fo, a0,a1,a2,a3);
            acc4(xt + (((size_t)cb) << 6) + fo, e0,e1,e2,e3);
            acc4(xt + (((size_t)cc) << 6) + fo, g0,g1,g2,g3);
            acc4(xt + (((size_t)cd) << 6) + fo, h0,h1,h2,h3);
        }
        for (; r < re; r++)
            acc4(xt + (((size_t)col[r]) << 6) + fo, a0,a1,a2,a3);
        a0 += e0 + g0 + h0;
        a1 += e1 + g1 + h1;
        a2 += e2 + g2 + h2;
        a3 += e3 + g3 + h3;
        ushort4 sv = *(const ushort4*)(xt + (((size_t)(nb+row)) << 6) + fo);
        a0 = fmaf(ep, bf2f_s((short)sv.x), a0);
        a1 = fmaf(ep, bf2f_s((short)sv.y), a1);
        a2 = fmaf(ep, bf2f_s((short)sv.z), a2);
        a3 = fmaf(ep, bf2f_s((short)sv.w), a3);
        short4 hh, ll;
        hh.x = f2bf_s(a0); ll.x = f2bf_s(a0 - bf2f_s(hh.x));
        hh.y = f2bf_s(a1); ll.y = f2bf_s(a1 - bf2f_s(hh.y));
        hh.z = f2bf_s(a2); ll.z = f2bf_s(a2 - bf2f_s(hh.z));
        hh.w = f2bf_s(a3); ll.w = f2bf_s(a3 - bf2f_s(hh.w));
        *(short4*)(Sh + row*72 + fo) = hh;
        *(short4*)(Sl + row*72 + fo) = ll;
    }
    __syncthreads();

    // ---- Phase 2: GEMM1 (A from LDS) ----
    short8 Ah[2][2], Al[2][2];
    #pragma unroll
    for (int mc=0; mc<2; mc++)
      #pragma unroll
      for (int kc=0; kc<2; kc++){
        Ah[mc][kc] = *(const short8*)(Sh + (mc*16+m)*72 + kc*32 + q*8);
        Al[mc][kc] = *(const short8*)(Sl + (mc*16+m)*72 + kc*32 + q*8);
      }
    floatx4 acc[2][4];
    #pragma unroll
    for (int mc=0;mc<2;mc++)
      #pragma unroll
      for (int nc=0;nc<4;nc++) acc[mc][nc] = (floatx4){0.f,0.f,0.f,0.f};
    #pragma unroll
    for (int nc=0;nc<4;nc++){
      #pragma unroll
      for (int kc=0;kc<2;kc++){
        short8 bh = *(const short8*)(w1h + (nc*16+m)*64 + kc*32 + q*8);
        short8 bl = *(const short8*)(w1l + (nc*16+m)*64 + kc*32 + q*8);
        #pragma unroll
        for (int mc=0;mc<2;mc++){
          acc[mc][nc] = __builtin_amdgcn_mfma_f32_16x16x32_bf16(Ah[mc][kc], bh, acc[mc][nc],0,0,0);
          acc[mc][nc] = __builtin_amdgcn_mfma_f32_16x16x32_bf16(Al[mc][kc], bh, acc[mc][nc],0,0,0);
          acc[mc][nc] = __builtin_amdgcn_mfma_f32_16x16x32_bf16(Ah[mc][kc], bl, acc[mc][nc],0,0,0);
        }
      }
    }

    // epilogue 1: bias + relu, split back into LDS
    #pragma unroll
    for (int nc=0;nc<4;nc++){
      float bia = b1[nc*16+m];
      #pragma unroll
      for (int mc=0;mc<2;mc++)
        #pragma unroll
        for (int r=0;r<4;r++){
          float v = fmaxf(acc[mc][nc][r] + bia, 0.f);
          int row = mc*16 + q*4 + r, cl = nc*16 + m;
          short hb = f2bf_s(v);
          Sh[row*72+cl] = hb;
          Sl[row*72+cl] = f2bf_s(v - bf2f_s(hb));
        }
    }
    __syncthreads();

    // GEMM2
    short8 A2h[2][2], A2l[2][2];
    #pragma unroll
    for (int mc=0; mc<2; mc++)
      #pragma unroll
      for (int kc=0; kc<2; kc++){
        A2h[mc][kc] = *(const short8*)(Sh + (mc*16+m)*72 + kc*32 + q*8);
        A2l[mc][kc] = *(const short8*)(Sl + (mc*16+m)*72 + kc*32 + q*8);
      }
    floatx4 acc2[2][4];
    #pragma unroll
    for (int mc=0;mc<2;mc++)
      #pragma unroll
      for (int nc=0;nc<4;nc++) acc2[mc][nc] = (floatx4){0.f,0.f,0.f,0.f};
    #pragma unroll
    for (int nc=0;nc<4;nc++){
      #pragma unroll
      for (int kc=0;kc<2;kc++){
        short8 bh = *(const short8*)(w2h + (nc*16+m)*64 + kc*32 + q*8);
        short8 bl = *(const short8*)(w2l + (nc*16+m)*64 + kc*32 + q*8);
        #pragma unroll
        for (int mc=0;mc<2;mc++){
          acc2[mc][nc] = __builtin_amdgcn_mfma_f32_16x16x32_bf16(A2h[mc][kc], bh, acc2[mc][nc],0,0,0);
          acc2[mc][nc] = __builtin_amdgcn_mfma_f32_16x16x32_bf16(A2l[mc][kc], bh, acc2[mc][nc],0,0,0);
          acc2[mc][nc] = __builtin_amdgcn_mfma_f32_16x16x32_bf16(A2h[mc][kc], bl, acc2[mc][nc],0,0,0);
        }
      }
    }

    // epilogue 2: bias, store h2 (bf16), BN stats (fp32-exact)
    #pragma unroll
    for (int nc=0;nc<4;nc++){
      float bia = b2[nc*16+m];
      float s = 0.f, s2 = 0.f;
      #pragma unroll
      for (int mc=0;mc<2;mc++)
        #pragma unroll
        for (int r=0;r<4;r++){
          float v = acc2[mc][nc][r] + bia;
          bigh[(((size_t)(nb + mc*16 + q*4 + r)) << 6) + nc*16 + m] =
              (unsigned short)f2bf_s(v);
          s += v; s2 = fmaf(v, v, s2);
        }
      s  += __shfl_xor(s, 16, 64);  s  += __shfl_xor(s, 32, 64);
      s2 += __shfl_xor(s2,16, 64);  s2 += __shfl_xor(s2,32, 64);
      if (q == 0){ red[0][wv][nc*16+m] = s; red[1][wv][nc*16+m] = s2; }
    }
    __syncthreads();
    if (tid < 128){
      int which = tid >> 6, c = tid & 63;
      float a = red[which][0][c]+red[which][1][c]+red[which][2][c]+red[which][3][c];
      unsafeAtomicAdd(stats + which*64 + c, a);
    }
}

// ------------------------------------------------------------------
// MFMA BN-apply (params inline from stats) + inner MLP + fused pool.
// ONLY change vs r0: big read is bf16.
// ------------------------------------------------------------------
__global__ __launch_bounds__(256) void k_bn_inner(
    const unsigned short* __restrict__ bigh, const float* __restrict__ stats,
    const float* __restrict__ gam, const float* __restrict__ bet,
    const short* __restrict__ wih, const short* __restrict__ wil,
    const float* __restrict__ bi,
    bf16* __restrict__ xh,
    const int* __restrict__ gidx, float* __restrict__ pooled)
{
    __shared__ __align__(16) char buf[4][9472];
    int tid = threadIdx.x, wv = tid >> 6, lane = tid & 63;
    int q = lane >> 4, m = lane & 15;
    int nb = blockIdx.x*128 + wv*32;
    short* Sh = (short*)buf[wv];
    short* Sl = Sh + 2304;

    // BN params inline (stats complete: previous dispatch)
    float mu  = stats[lane]    * (1.0f/NN);
    float ex2 = stats[64+lane] * (1.0f/NN);
    float var = ex2 - mu*mu;
    float sc  = gam[lane] * rsqrtf(var + 1e-5f);
    float sh  = bet[lane] - mu*sc;

    for (int rr = 0; rr < 32; rr++){
        float v = bf2f_s((short)bigh[(((size_t)(nb+rr)) << 6) + lane]);
        v = fmaxf(fmaf(v, sc, sh), 0.f);
        xh[(((size_t)(nb+rr)) << 6) + lane] = __float2bfloat16(v);
        short hb = f2bf_s(v);
        Sh[rr*72 + lane] = hb;
        Sl[rr*72 + lane] = f2bf_s(v - bf2f_s(hb));
    }
    __syncthreads();

    short8 A2h[2][2], A2l[2][2];
    #pragma unroll
    for (int mc=0; mc<2; mc++)
      #pragma unroll
      for (int kc=0; kc<2; kc++){
        A2h[mc][kc] = *(const short8*)(Sh + (mc*16+m)*72 + kc*32 + q*8);
        A2l[mc][kc] = *(const short8*)(Sl + (mc*16+m)*72 + kc*32 + q*8);
      }
    floatx4 acc[2][4];
    #pragma unroll
    for (int mc=0;mc<2;mc++)
      #pragma unroll
      for (int nc=0;nc<4;nc++) acc[mc][nc] = (floatx4){0.f,0.f,0.f,0.f};
    #pragma unroll
    for (int nc=0;nc<4;nc++){
      #pragma unroll
      for (int kc=0;kc<2;kc++){
        short8 bh = *(const short8*)(wih + (nc*16+m)*64 + kc*32 + q*8);
        short8 bl = *(const short8*)(wil + (nc*16+m)*64 + kc*32 + q*8);
        #pragma unroll
        for (int mc=0;mc<2;mc++){
          acc[mc][nc] = __builtin_amdgcn_mfma_f32_16x16x32_bf16(A2h[mc][kc], bh, acc[mc][nc],0,0,0);
          acc[mc][nc] = __builtin_amdgcn_mfma_f32_16x16x32_bf16(A2l[mc][kc], bh, acc[mc][nc],0,0,0);
          acc[mc][nc] = __builtin_amdgcn_mfma_f32_16x16x32_bf16(A2h[mc][kc], bl, acc[mc][nc],0,0,0);
        }
      }
    }
    __syncthreads();   // LDS reads done; safe to repurpose buf

    float* P = (float*)buf[wv];
    #pragma unroll
    for (int nc=0;nc<4;nc++){
      float bia = bi[nc*16+m];
      #pragma unroll
      for (int mc=0;mc<2;mc++)
        #pragma unroll
        for (int r=0;r<4;r++){
          float v = fmaxf(acc[mc][nc][r] + bia, 0.f);
          P[(mc*16 + q*4 + r)*66 + nc*16 + m] = v;
        }
    }
    __syncthreads();

    int gv = (lane < 32) ? gidx[nb + lane] : 0;
    int cur = __shfl(gv, 0, 64);
    float a = 0.f;
    for (int rr = 0; rr < 32; rr++){
        int g = __shfl(gv, rr, 64);
        if (g != cur){
            unsafeAtomicAdd(pooled + (size_t)cur*64 + lane, a);
            a = 0.f; cur = g;
        }
        a += P[rr*66 + lane];
    }
    unsafeAtomicAdd(pooled + (size_t)cur*64 + lane, a);
}

// ------------------------------------------------------------------
// Tail: TG graphs per block; corpus layer-2 outer computed inline.
// ------------------------------------------------------------------
__global__ __launch_bounds__(256) void k_tail(
    const float* __restrict__ qf, const float* __restrict__ cf,
    const float* __restrict__ pooled_c2,
    const float* __restrict__ ow2, const float* __restrict__ ob2,
    const float* __restrict__ cw1, const float* __restrict__ cb1,
    const float* __restrict__ cw2, const float* __restrict__ cb2,
    const float* __restrict__ sw1, const float* __restrict__ sb1,
    const float* __restrict__ sw2, const float* __restrict__ sb2,
    const float* __restrict__ nw,  const float* __restrict__ nwb,
    const float* __restrict__ nb,
    const float* __restrict__ mw1, const float* __restrict__ mb1,
    const float* __restrict__ mw2, const float* __restrict__ mb2,
    const float* __restrict__ alpha, const float* __restrict__ beta,
    float* __restrict__ out)
{
    __shared__ float cws[192*96];
    __shared__ float diff[TG][192];
    __shared__ float e1s[TG][64], e2s[TG][64];
    __shared__ float h1s[TG][96], h2s[TG][96];
    __shared__ float s1s[TG][16], s2s[TG][16], srep[TG][16];
    __shared__ float red[16][16][TG];

    int t = threadIdx.x;
    int b0 = blockIdx.x * TG;

    // inline corpus outer (layer 2): e2s = relu(pooled_c2 @ ow2 + ob2)
    {
        int b = t >> 5, o = (t & 31) * 2;
        const float* pr = pooled_c2 + (size_t)(b0 + b)*64;
        float a0 = ob2[o], a1 = ob2[o+1];
        for (int k = 0; k < 64; k++) {
            float p = pr[k];
            a0 = fmaf(p, ow2[k*64 + o], a0);
            a1 = fmaf(p, ow2[k*64 + o + 1], a1);
        }
        e2s[b][o]   = fmaxf(a0, 0.f);
        e2s[b][o+1] = fmaxf(a1, 0.f);
    }
    for (int i = t; i < 192*96; i += 256) cws[i] = cw1[i];
    __syncthreads();

    for (int i = t; i < TG*192; i += 256) {
        int b = i / 192, f = i % 192;
        float qv = qf[(b0+b)*192 + f];
        float cv = (f < 128) ? cf[(b0+b)*192 + f] : e2s[b][f-128];
        float d = qv - cv;
        diff[b][f] = __expf(-d*d);
        if (f >= 128) e1s[b][f-128] = qv;
    }
    __syncthreads();

    {
        int b = t >> 5, o = (t & 31) * 3;
        float a0 = cb1[o], a1 = cb1[o+1], a2 = cb1[o+2];
        for (int f = 0; f < 192; f++) {
            float d = diff[b][f];
            const float* w = cws + f*96 + o;
            a0 = fmaf(d, w[0], a0);
            a1 = fmaf(d, w[1], a1);
            a2 = fmaf(d, w[2], a2);
        }
        h1s[b][o] = fmaxf(a0, 0.f);
        h1s[b][o+1] = fmaxf(a1, 0.f);
        h1s[b][o+2] = fmaxf(a2, 0.f);
    }
    __syncthreads();
    for (int i = t; i < 96*96; i += 256) cws[i] = cw2[i];
    __syncthreads();
    {
        int b = t >> 5, o = (t & 31) * 3;
        float a0 = cb2[o], a1 = cb2[o+1], a2 = cb2[o+2];
        for (int f = 0; f < 96; f++) {
            float d = h1s[b][f];
            const float* w = cws + f*96 + o;
            a0 = fmaf(d, w[0], a0);
            a1 = fmaf(d, w[1], a1);
            a2 = fmaf(d, w[2], a2);
        }
        h2s[b][o] = tanhf(a0);
        h2s[b][o+1] = tanhf(a1);
        h2s[b][o+2] = tanhf(a2);
    }
    __syncthreads();
    if (t < TG*16) {
        int b = t >> 4, o = t & 15;
        float a = sb1[o];
        for (int f = 0; f < 96; f++) a = fmaf(h2s[b][f], sw1[f*16+o], a);
        s1s[b][o] = fmaxf(a, 0.f);
    }

    {
        int tt = t & 15, gq = t >> 4;
        int g0 = gq * 4;
        int lane = t & 63;
        float e1v[TG];
        #pragma unroll
        for (int b = 0; b < TG; b++) e1v[b] = e1s[b][lane];
        float v0[TG], v1[TG], v2[TG], v3[TG];
        #pragma unroll
        for (int b = 0; b < TG; b++) { v0[b]=0.f; v1[b]=0.f; v2[b]=0.f; v3[b]=0.f; }
        for (int f = 0; f < 64; f++) {
            const float* wp = nw + ((size_t)f*64 + g0)*16 + tt;
            float w0 = wp[0], w1 = wp[16], w2 = wp[32], w3 = wp[48];
            #pragma unroll
            for (int b = 0; b < TG; b++) {
                float e = __shfl(e1v[b], f, 64);
                v0[b] = fmaf(e, w0, v0[b]);
                v1[b] = fmaf(e, w1, v1[b]);
                v2[b] = fmaf(e, w2, v2[b]);
                v3[b] = fmaf(e, w3, v3[b]);
            }
        }
        #pragma unroll
        for (int b = 0; b < TG; b++) {
            float p = v0[b]*e2s[b][g0] + v1[b]*e2s[b][g0+1]
                    + v2[b]*e2s[b][g0+2] + v3[b]*e2s[b][g0+3];
            red[gq][tt][b] = p;
        }
    }
    __syncthreads();
    if (t < TG*16) {
        int b = t >> 4, tt = t & 15;
        float scv = 0.f;
        #pragma unroll
        for (int gq = 0; gq < 16; gq++) scv += red[gq][tt][b];
        float blk = nb[tt];
        for (int f = 0; f < 64; f++) blk = fmaf(e1s[b][f], nwb[tt*128 + f], blk);
        for (int f = 0; f < 64; f++) blk = fmaf(e2s[b][f], nwb[tt*128 + 64 + f], blk);
        srep[b][tt] = fmaxf(scv + blk, 0.f);
    }
    __syncthreads();
    if (t < TG*16) {
        int b = t >> 4, o = t & 15;
        float a = mb1[o];
        #pragma unroll
        for (int f = 0; f < 16; f++) a = fmaf(srep[b][f], mw1[f*16+o], a);
        s2s[b][o] = fmaxf(a, 0.f);
    }
    __syncthreads();
    if (t < TG) {
        float sco = sb2[0], sm = mb2[0];
        #pragma unroll
        for (int f = 0; f < 16; f++) {
            sco = fmaf(s1s[t][f], sw2[f], sco);
            sm  = fmaf(s2s[t][f], mw2[f], sm);
        }
        float score = 1.f / (1.f + __expf(-sco));
        float sim   = 1.f / (1.f + __expf(-sm));
        out[b0 + t] = alpha[0]*score + beta[0]*sim;
    }
}

// ------------------------------------------------------------------
extern "C" void kernel_launch(void* const* d_in, const int* in_sizes, int n_in,
                              void* d_out, int out_size, void* d_ws, size_t ws_size,
                              hipStream_t stream)
{
    const float* qx  = (const float*)d_in[0];
    const float* cx  = (const float*)d_in[1];
    const int*   qei = (const int*)d_in[2];
    const int*   cei = (const int*)d_in[3];
    const int*   qgi = (const int*)d_in[4];
    const int*   cgi = (const int*)d_in[5];
    const float* Wgw1 = (const float*)d_in[6];
    const float* Wgb1 = (const float*)d_in[7];
    const float* Wgw2 = (const float*)d_in[8];
    const float* Wgb2 = (const float*)d_in[9];
    const float* Wgam = (const float*)d_in[10];
    const float* Wbet = (const float*)d_in[11];
    const float* Weps = (const float*)d_in[12];
    const float* Wiw  = (const float*)d_in[13];
    const float* Wib  = (const float*)d_in[14];
    const float* Wow  = (const float*)d_in[15];
    const float* Wob  = (const float*)d_in[16];
    const float* Wcw1 = (const float*)d_in[17];
    const float* Wcb1 = (const float*)d_in[18];
    const float* Wcw2 = (const float*)d_in[19];
    const float* Wcb2 = (const float*)d_in[20];
    const float* Wsw1 = (const float*)d_in[21];
    const float* Wsb1 = (const float*)d_in[22];
    const float* Wsw2 = (const float*)d_in[23];
    const float* Wsb2 = (const float*)d_in[24];
    const float* Wnw  = (const float*)d_in[25];
    const float* Wnwb = (const float*)d_in[26];
    const float* Wnb  = (const float*)d_in[27];
    const float* Wmw1 = (const float*)d_in[28];
    const float* Wmb1 = (const float*)d_in[29];
    const float* Wmw2 = (const float*)d_in[30];
    const float* Wmb2 = (const float*)d_in[31];
    const float* Wal  = (const float*)d_in[32];
    const float* Wbe  = (const float*)d_in[33];

    float* F      = (float*)d_ws;
    float* big    = F;                        // region: h2 bf16 (8MB used of 33.5MB); rank aliases
    float* zbuf   = F + 8388608;              // stats3(384) + pooled3(196608)
    float* stats3 = zbuf;
    float* pooled3= zbuf + 384;
    float* qf     = pooled3 + 3*BG*64;        // BG*192
    float* cf     = qf + 196608;              // BG*192
    int*   rowptr = (int*)(cf + 196608);      // NN+1
    int*   cnt    = rowptr + (NN + 1);        // NN (histogram)
    int*   col    = cnt + NN;                 // NEDGE
    int*   bsum   = col + NEDGE;              // 128
    int*   boff   = bsum + 128;               // 128
    bf16*  xh     = (bf16*)(boff + 128);      // N*64 bf16
    int*   rank   = (int*)big;                // NEDGE (dead during CSR build)
    unsigned short* bigh = (unsigned short*)big;  // N*64 bf16 (h2)
    uintptr_t wtb = (uintptr_t)(xh + (size_t)NN*64);
    wtb = (wtb + 63) & ~((uintptr_t)63);
    short* w1h = (short*)wtb;                 // 3*4096 each
    short* w1l = w1h + 3*4096;
    short* w2h = w1l + 3*4096;
    short* w2l = w2h + 3*4096;
    short* wih = w2l + 3*4096;
    short* wil = wih + 3*4096;

    k_wprep<<<144, 256, 0, stream>>>(Wgw1, Wgw2, Wiw, w1h, w1l, w2h, w2l, wih, wil);

    for (int side = 0; side < 2; side++) {
        const float* x0 = side ? cx  : qx;
        const int* ei   = side ? cei : qei;
        const int* gi   = side ? cgi : qgi;
        float* feats    = side ? cf  : qf;

        // side 1's k_zero also performs outer(l=2) for side 0 (qf cols 128..191)
        if (side == 0)
            k_zero<<<NN/256, 256, 0, stream>>>(cnt, nullptr, nullptr, nullptr, nullptr);
        else
            k_zero<<<NN/256, 256, 0, stream>>>(cnt, pooled3 + 2*BG*64,
                                               Wow + 2*4096, Wob + 2*64, qf);
        k_hist<<<NEDGE/256, 256, 0, stream>>>(ei, cnt, rank);
        k_scan1<<<128, 256, 0, stream>>>(cnt, rowptr, bsum);
        k_scan2<<<1, 128, 0, stream>>>(bsum, boff, rowptr);
        k_scan3<<<NN/256, 256, 0, stream>>>(rowptr, boff);
        k_fill<<<NEDGE/256, 256, 0, stream>>>(ei, rowptr, rank, col);

        k_cvt<<<NN*64/1024, 256, 0, stream>>>(x0, xh, zbuf);

        for (int l = 0; l < LAYERS; l++) {
            const float* pprev = (l == 0) ? nullptr : pooled3 + (size_t)(l-1)*BG*64;
            const float* owp   = (l == 0) ? nullptr : Wow + (l-1)*4096;
            const float* obp   = (l == 0) ? nullptr : Wob + (l-1)*64;
            k_agg_gin<<<NN/128, 256, 0, stream>>>(xh, rowptr, col, Weps + l,
                                                  w1h + l*4096, w1l + l*4096, Wgb1 + l*64,
                                                  w2h + l*4096, w2l + l*4096, Wgb2 + l*64,
                                                  bigh, stats3 + l*128,
                                                  pprev, owp, obp, feats, (l-1)*64);
            k_bn_inner<<<NN/128, 256, 0, stream>>>(bigh, stats3 + l*128,
                                                   Wgam + l*64, Wbet + l*64,
                                                   wih + l*4096, wil + l*4096,
                                                   Wib + l*64, xh, gi,
                                                   pooled3 + (size_t)l*BG*64);
        }
    }

    k_tail<<<BG/TG, 256, 0, stream>>>(qf, cf, pooled3 + 2*BG*64,
                                      Wow + 2*4096, Wob + 2*64,
                                      Wcw1, Wcb1, Wcw2, Wcb2,
                                      Wsw1, Wsb1, Wsw2, Wsb2,
                                      Wnw, Wnwb, Wnb, Wmw1, Wmb1, Wmw2, Wmb2,
                                      Wal, Wbe, (float*)d_out);
}

// Round 8
// 819.549 us; speedup vs baseline: 1.3656x; 1.1084x over previous
//
#include <hip/hip_runtime.h>
#include <hip/hip_bf16.h>

typedef __hip_bfloat16 bf16;
typedef __attribute__((ext_vector_type(8))) short short8;
typedef __attribute__((ext_vector_type(4))) float floatx4;

#define NN     131072
#define NEDGE  1048576
#define BG     1024
#define LAYERS 3
#define TG     8      // graphs per tail block
#define ZTOTM  (768 + 6*BG*64)   // merged: stats3 (2x3x128) + pooled3 (2x3xBGx64)

// bf16 split helpers (RNE)
__device__ __forceinline__ short f2bf_s(float f){
    union { float f; unsigned u; } x; x.f = f;
    unsigned r = x.u + 0x7fffu + ((x.u >> 16) & 1u);
    return (short)(r >> 16);
}
__device__ __forceinline__ float bf2f_s(short s){
    union { unsigned u; float f; } x; x.u = ((unsigned)(unsigned short)s) << 16;
    return x.f;
}
__device__ __forceinline__ void acc4(const unsigned short* p,
                                     float& a0, float& a1, float& a2, float& a3){
    ushort4 u = *(const ushort4*)p;
    a0 += bf2f_s((short)u.x); a1 += bf2f_s((short)u.y);
    a2 += bf2f_s((short)u.z); a3 += bf2f_s((short)u.w);
}

// ==================================================================
// Shared: weight prep (once/launch): Wt[n][k] = W[k][n], bf16 hi/lo.
// ==================================================================
__global__ __launch_bounds__(256) void k_wprep(
    const float* __restrict__ gw1, const float* __restrict__ gw2,
    const float* __restrict__ iw,
    short* __restrict__ w1h, short* __restrict__ w1l,
    short* __restrict__ w2h, short* __restrict__ w2l,
    short* __restrict__ wih, short* __restrict__ wil)
{
    int i = blockIdx.x*256 + threadIdx.x;
    if (i >= 3*LAYERS*4096) return;
    int msel = i / (LAYERS*4096);
    int rem  = i % (LAYERS*4096);
    int l = rem >> 12, idx = rem & 4095;
    int n = idx >> 6, k = idx & 63;
    const float* src = (msel==0) ? gw1 : (msel==1) ? gw2 : iw;
    float v = src[l*4096 + k*64 + n];
    short hi = f2bf_s(v);
    short lo = f2bf_s(v - bf2f_s(hi));
    short* dh = (msel==0) ? w1h : (msel==1) ? w2h : wih;
    short* dl = (msel==0) ? w1l : (msel==1) ? w2l : wil;
    dh[rem] = hi;
    dl[rem] = lo;
}

// ==================================================================
// ===================== MERGED-GRAPH PATH (M) ======================
// Both sides as one 2N-node / 2M-edge graph; 13 dispatches total.
// ==================================================================
__global__ __launch_bounds__(256) void k_cvtM(const float* __restrict__ qx,
                                              const float* __restrict__ cx,
                                              bf16* __restrict__ xh,
                                              int* __restrict__ cnt,
                                              float* __restrict__ zbuf)
{
    int i = blockIdx.x*256 + threadIdx.x;   // 16384 blocks -> 2*NN*16 quads
    float4 v = (i < NN*16) ? ((const float4*)qx)[i]
                           : ((const float4*)cx)[i - NN*16];
    short4 o;
    o.x = f2bf_s(v.x); o.y = f2bf_s(v.y);
    o.z = f2bf_s(v.z); o.w = f2bf_s(v.w);
    ((short4*)xh)[i] = o;
    if (i < 2*NN)   cnt[i]  = 0;
    if (i < ZTOTM)  zbuf[i] = 0.f;
}

__global__ __launch_bounds__(256) void k_histM(const int* __restrict__ qei,
                                               const int* __restrict__ cei,
                                               int* __restrict__ cnt,
                                               int* __restrict__ rank)
{
    int e = blockIdx.x*256 + threadIdx.x;   // 8192 blocks -> 2M edges
    int side = e >> 20;                     // NEDGE = 1<<20
    int el = e & (NEDGE-1);
    const int* ei = side ? cei : qei;
    rank[e] = atomicAdd(cnt + ei[NEDGE + el] + side*NN, 1);
}

__global__ __launch_bounds__(256) void k_scan1M(const int* __restrict__ cnt,
    int* __restrict__ rowptr, int* __restrict__ bsum)
{
    __shared__ int sd[256];
    int t = threadIdx.x;
    int base = blockIdx.x*1024 + t*4;       // grid 256 -> 2NN entries
    int c0 = cnt[base], c1 = cnt[base+1], c2 = cnt[base+2], c3 = cnt[base+3];
    int tsum = c0 + c1 + c2 + c3;
    sd[t] = tsum;
    __syncthreads();
    for (int off = 1; off < 256; off <<= 1) {
        int v = (t >= off) ? sd[t-off] : 0;
        __syncthreads();
        sd[t] += v;
        __syncthreads();
    }
    int excl = sd[t] - tsum;
    rowptr[base]   = excl;
    rowptr[base+1] = excl + c0;
    rowptr[base+2] = excl + c0 + c1;
    rowptr[base+3] = excl + c0 + c1 + c2;
    if (t == 255) bsum[blockIdx.x] = sd[255];
}

__global__ __launch_bounds__(256) void k_scan2M(const int* __restrict__ bsum,
    int* __restrict__ boff, int* __restrict__ rowptr)
{
    __shared__ int sd[256];
    int t = threadIdx.x;
    int v0 = bsum[t];
    sd[t] = v0;
    __syncthreads();
    for (int off = 1; off < 256; off <<= 1) {
        int v = (t >= off) ? sd[t-off] : 0;
        __syncthreads();
        sd[t] += v;
        __syncthreads();
    }
    boff[t] = sd[t] - v0;
    if (t == 0) rowptr[2*NN] = 2*NEDGE;
}

__global__ __launch_bounds__(256) void k_scan3M(int* __restrict__ rowptr,
    const int* __restrict__ boff)
{
    int i = blockIdx.x*256 + threadIdx.x;   // grid 1024 -> 2NN
    rowptr[i] += boff[i >> 10];
}

__global__ __launch_bounds__(256) void k_fillM(const int* __restrict__ qei,
    const int* __restrict__ cei,
    const int* __restrict__ rowptr, const int* __restrict__ rank,
    int* __restrict__ col)
{
    int e = blockIdx.x*256 + threadIdx.x;
    int side = e >> 20;
    int el = e & (NEDGE-1);
    const int* ei = side ? cei : qei;
    int s = ei[el] + side*NN;
    int d = ei[NEDGE + el] + side*NN;
    col[rowptr[d] + rank[e]] = s;
}

__global__ __launch_bounds__(256) void k_agg_ginM(
    const bf16* __restrict__ xh,
    const int* __restrict__ rowptr, const int* __restrict__ col,
    const float* __restrict__ epsp,
    const short* __restrict__ w1h, const short* __restrict__ w1l,
    const float* __restrict__ b1,
    const short* __restrict__ w2h, const short* __restrict__ w2l,
    const float* __restrict__ b2,
    unsigned short* __restrict__ bigh, float* __restrict__ stats,
    const float* __restrict__ pprev_q, const float* __restrict__ pprev_c,
    const float* __restrict__ owp, const float* __restrict__ obp,
    float* __restrict__ qf, float* __restrict__ cf, int coffp)
{
    __shared__ __align__(16) char buf[4][9472];
    __shared__ float red[2][4][64];
    int bid = blockIdx.x;
    int side = bid >> 10;
    int lb = bid & 1023;
    int tid = threadIdx.x, wv = tid >> 6, lane = tid & 63;
    int q = lane >> 4, m = lane & 15;
    int nb = bid*128 + wv*32;          // global node base
    short* Sh = (short*)buf[wv];
    short* Sl = Sh + 2304;      // 32*72
    float ep = 1.0f + *epsp;

    // folded outer MLP of previous layer (both sides, 256 blocks each)
    if (owp && lb < 256) {
        int g = lb*256 + tid;
        int bb = g >> 6, j = g & 63;
        const float* pr = (side ? pprev_c : pprev_q) + bb*64;
        float a = obp[j];
        for (int k = 0; k < 64; k++) a = fmaf(pr[k], owp[k*64 + j], a);
        float* feats = side ? cf : qf;
        feats[bb*192 + coffp + j] = fmaxf(a, 0.f);
    }

    // ---- Phase 1: group-per-node gather (r0/r6-exact geometry) ----
    int gv = rowptr[nb + (lane < 33 ? lane : 32)];
    int fo = m * 4;
    const unsigned short* xt = (const unsigned short*)xh;

    for (int i = 0; i < 8; i++) {
        int row = i*4 + q;
        int rs = __shfl(gv, row, 64);
        int re = __shfl(gv, row+1, 64);
        float a0=0.f,a1=0.f,a2=0.f,a3=0.f;
        float e0=0.f,e1=0.f,e2=0.f,e3=0.f;
        float g0=0.f,g1=0.f,g2=0.f,g3=0.f;
        float h0=0.f,h1=0.f,h2=0.f,h3=0.f;
        int r = rs;
        for (; r + 4 <= re; r += 4) {
            int ca = col[r], cb = col[r+1], cc = col[r+2], cd = col[r+3];
            acc4(xt + (((size_t)ca) << 6) + fo, a0,a1,a2,a3);
            acc4(xt + (((size_t)cb) << 6) + fo, e0,e1,e2,e3);
            acc4(xt + (((size_t)cc) << 6) + fo, g0,g1,g2,g3);
            acc4(xt + (((size_t)cd) << 6) + fo, h0,h1,h2,h3);
        }
        for (; r < re; r++)
            acc4(xt + (((size_t)col[r]) << 6) + fo, a0,a1,a2,a3);
        a0 += e0 + g0 + h0;
        a1 += e1 + g1 + h1;
        a2 += e2 + g2 + h2;
        a3 += e3 + g3 + h3;
        ushort4 sv = *(const ushort4*)(xt + (((size_t)(nb+row)) << 6) + fo);
        a0 = fmaf(ep, bf2f_s((short)sv.x), a0);
        a1 = fmaf(ep, bf2f_s((short)sv.y), a1);
        a2 = fmaf(ep, bf2f_s((short)sv.z), a2);
        a3 = fmaf(ep, bf2f_s((short)sv.w), a3);
        short4 hh, ll;
        hh.x = f2bf_s(a0); ll.x = f2bf_s(a0 - bf2f_s(hh.x));
        hh.y = f2bf_s(a1); ll.y = f2bf_s(a1 - bf2f_s(hh.y));
        hh.z = f2bf_s(a2); ll.z = f2bf_s(a2 - bf2f_s(hh.z));
        hh.w = f2bf_s(a3); ll.w = f2bf_s(a3 - bf2f_s(hh.w));
        *(short4*)(Sh + row*72 + fo) = hh;
        *(short4*)(Sl + row*72 + fo) = ll;
    }
    __syncthreads();

    // ---- Phase 2: GEMM1 ----
    short8 Ah[2][2], Al[2][2];
    #pragma unroll
    for (int mc=0; mc<2; mc++)
      #pragma unroll
      for (int kc=0; kc<2; kc++){
        Ah[mc][kc] = *(const short8*)(Sh + (mc*16+m)*72 + kc*32 + q*8);
        Al[mc][kc] = *(const short8*)(Sl + (mc*16+m)*72 + kc*32 + q*8);
      }
    floatx4 acc[2][4];
    #pragma unroll
    for (int mc=0;mc<2;mc++)
      #pragma unroll
      for (int nc=0;nc<4;nc++) acc[mc][nc] = (floatx4){0.f,0.f,0.f,0.f};
    #pragma unroll
    for (int nc=0;nc<4;nc++){
      #pragma unroll
      for (int kc=0;kc<2;kc++){
        short8 bh = *(const short8*)(w1h + (nc*16+m)*64 + kc*32 + q*8);
        short8 bl = *(const short8*)(w1l + (nc*16+m)*64 + kc*32 + q*8);
        #pragma unroll
        for (int mc=0;mc<2;mc++){
          acc[mc][nc] = __builtin_amdgcn_mfma_f32_16x16x32_bf16(Ah[mc][kc], bh, acc[mc][nc],0,0,0);
          acc[mc][nc] = __builtin_amdgcn_mfma_f32_16x16x32_bf16(Al[mc][kc], bh, acc[mc][nc],0,0,0);
          acc[mc][nc] = __builtin_amdgcn_mfma_f32_16x16x32_bf16(Ah[mc][kc], bl, acc[mc][nc],0,0,0);
        }
      }
    }

    #pragma unroll
    for (int nc=0;nc<4;nc++){
      float bia = b1[nc*16+m];
      #pragma unroll
      for (int mc=0;mc<2;mc++)
        #pragma unroll
        for (int r=0;r<4;r++){
          float v = fmaxf(acc[mc][nc][r] + bia, 0.f);
          int row = mc*16 + q*4 + r, cl = nc*16 + m;
          short hb = f2bf_s(v);
          Sh[row*72+cl] = hb;
          Sl[row*72+cl] = f2bf_s(v - bf2f_s(hb));
        }
    }
    __syncthreads();

    // GEMM2
    short8 A2h[2][2], A2l[2][2];
    #pragma unroll
    for (int mc=0; mc<2; mc++)
      #pragma unroll
      for (int kc=0; kc<2; kc++){
        A2h[mc][kc] = *(const short8*)(Sh + (mc*16+m)*72 + kc*32 + q*8);
        A2l[mc][kc] = *(const short8*)(Sl + (mc*16+m)*72 + kc*32 + q*8);
      }
    floatx4 acc2[2][4];
    #pragma unroll
    for (int mc=0;mc<2;mc++)
      #pragma unroll
      for (int nc=0;nc<4;nc++) acc2[mc][nc] = (floatx4){0.f,0.f,0.f,0.f};
    #pragma unroll
    for (int nc=0;nc<4;nc++){
      #pragma unroll
      for (int kc=0;kc<2;kc++){
        short8 bh = *(const short8*)(w2h + (nc*16+m)*64 + kc*32 + q*8);
        short8 bl = *(const short8*)(w2l + (nc*16+m)*64 + kc*32 + q*8);
        #pragma unroll
        for (int mc=0;mc<2;mc++){
          acc2[mc][nc] = __builtin_amdgcn_mfma_f32_16x16x32_bf16(A2h[mc][kc], bh, acc2[mc][nc],0,0,0);
          acc2[mc][nc] = __builtin_amdgcn_mfma_f32_16x16x32_bf16(A2l[mc][kc], bh, acc2[mc][nc],0,0,0);
          acc2[mc][nc] = __builtin_amdgcn_mfma_f32_16x16x32_bf16(A2h[mc][kc], bl, acc2[mc][nc],0,0,0);
        }
      }
    }

    // epilogue 2: bias, store h2 (bf16), BN stats per side
    #pragma unroll
    for (int nc=0;nc<4;nc++){
      float bia = b2[nc*16+m];
      float s = 0.f, s2 = 0.f;
      #pragma unroll
      for (int mc=0;mc<2;mc++)
        #pragma unroll
        for (int r=0;r<4;r++){
          float v = acc2[mc][nc][r] + bia;
          bigh[(((size_t)(nb + mc*16 + q*4 + r)) << 6) + nc*16 + m] =
              (unsigned short)f2bf_s(v);
          s += v; s2 = fmaf(v, v, s2);
        }
      s  += __shfl_xor(s, 16, 64);  s  += __shfl_xor(s, 32, 64);
      s2 += __shfl_xor(s2,16, 64);  s2 += __shfl_xor(s2,32, 64);
      if (q == 0){ red[0][wv][nc*16+m] = s; red[1][wv][nc*16+m] = s2; }
    }
    __syncthreads();
    if (tid < 128){
      int which = tid >> 6, c = tid & 63;
      float a = red[which][0][c]+red[which][1][c]+red[which][2][c]+red[which][3][c];
      unsafeAtomicAdd(stats + side*128 + which*64 + c, a);
    }
}

__global__ __launch_bounds__(256) void k_bn_innerM(
    const unsigned short* __restrict__ bigh, const float* __restrict__ stats,
    const float* __restrict__ gam, const float* __restrict__ bet,
    const short* __restrict__ wih, const short* __restrict__ wil,
    const float* __restrict__ bi,
    bf16* __restrict__ xh,
    const int* __restrict__ gidx_q, const int* __restrict__ gidx_c,
    float* __restrict__ pooled_q, float* __restrict__ pooled_c)
{
    __shared__ __align__(16) char buf[4][9472];
    int bid = blockIdx.x;
    int side = bid >> 10;
    int tid = threadIdx.x, wv = tid >> 6, lane = tid & 63;
    int q = lane >> 4, m = lane & 15;
    int nb = bid*128 + wv*32;          // global
    short* Sh = (short*)buf[wv];
    short* Sl = Sh + 2304;

    const float* st = stats + side*128;
    float mu  = st[lane]    * (1.0f/NN);
    float ex2 = st[64+lane] * (1.0f/NN);
    float var = ex2 - mu*mu;
    float sc  = gam[lane] * rsqrtf(var + 1e-5f);
    float sh  = bet[lane] - mu*sc;

    for (int rr = 0; rr < 32; rr++){
        float v = bf2f_s((short)bigh[(((size_t)(nb+rr)) << 6) + lane]);
        v = fmaxf(fmaf(v, sc, sh), 0.f);
        xh[(((size_t)(nb+rr)) << 6) + lane] = __float2bfloat16(v);
        short hb = f2bf_s(v);
        Sh[rr*72 + lane] = hb;
        Sl[rr*72 + lane] = f2bf_s(v - bf2f_s(hb));
    }
    __syncthreads();

    short8 A2h[2][2], A2l[2][2];
    #pragma unroll
    for (int mc=0; mc<2; mc++)
      #pragma unroll
      for (int kc=0; kc<2; kc++){
        A2h[mc][kc] = *(const short8*)(Sh + (mc*16+m)*72 + kc*32 + q*8);
        A2l[mc][kc] = *(const short8*)(Sl + (mc*16+m)*72 + kc*32 + q*8);
      }
    floatx4 acc[2][4];
    #pragma unroll
    for (int mc=0;mc<2;mc++)
      #pragma unroll
      for (int nc=0;nc<4;nc++) acc[mc][nc] = (floatx4){0.f,0.f,0.f,0.f};
    #pragma unroll
    for (int nc=0;nc<4;nc++){
      #pragma unroll
      for (int kc=0;kc<2;kc++){
        short8 bh = *(const short8*)(wih + (nc*16+m)*64 + kc*32 + q*8);
        short8 bl = *(const short8*)(wil + (nc*16+m)*64 + kc*32 + q*8);
        #pragma unroll
        for (int mc=0;mc<2;mc++){
          acc[mc][nc] = __builtin_amdgcn_mfma_f32_16x16x32_bf16(A2h[mc][kc], bh, acc[mc][nc],0,0,0);
          acc[mc][nc] = __builtin_amdgcn_mfma_f32_16x16x32_bf16(A2l[mc][kc], bh, acc[mc][nc],0,0,0);
          acc[mc][nc] = __builtin_amdgcn_mfma_f32_16x16x32_bf16(A2h[mc][kc], bl, acc[mc][nc],0,0,0);
        }
      }
    }
    __syncthreads();

    float* P = (float*)buf[wv];
    #pragma unroll
    for (int nc=0;nc<4;nc++){
      float bia = bi[nc*16+m];
      #pragma unroll
      for (int mc=0;mc<2;mc++)
        #pragma unroll
        for (int r=0;r<4;r++){
          float v = fmaxf(acc[mc][nc][r] + bia, 0.f);
          P[(mc*16 + q*4 + r)*66 + nc*16 + m] = v;
        }
    }
    __syncthreads();

    const int* gidx = side ? gidx_c : gidx_q;
    float* pooled   = side ? pooled_c : pooled_q;
    int ln = nb - side*NN;
    int gv = (lane < 32) ? gidx[ln + lane] : 0;
    int cur = __shfl(gv, 0, 64);
    float a = 0.f;
    for (int rr = 0; rr < 32; rr++){
        int g = __shfl(gv, rr, 64);
        if (g != cur){
            unsafeAtomicAdd(pooled + (size_t)cur*64 + lane, a);
            a = 0.f; cur = g;
        }
        a += P[rr*66 + lane];
    }
    unsafeAtomicAdd(pooled + (size_t)cur*64 + lane, a);
}

__global__ __launch_bounds__(256) void k_tailM(
    const float* __restrict__ qf, const float* __restrict__ cf,
    const float* __restrict__ pooled_q2, const float* __restrict__ pooled_c2,
    const float* __restrict__ ow2, const float* __restrict__ ob2,
    const float* __restrict__ cw1, const float* __restrict__ cb1,
    const float* __restrict__ cw2, const float* __restrict__ cb2,
    const float* __restrict__ sw1, const float* __restrict__ sb1,
    const float* __restrict__ sw2, const float* __restrict__ sb2,
    const float* __restrict__ nw,  const float* __restrict__ nwb,
    const float* __restrict__ nb,
    const float* __restrict__ mw1, const float* __restrict__ mb1,
    const float* __restrict__ mw2, const float* __restrict__ mb2,
    const float* __restrict__ alpha, const float* __restrict__ beta,
    float* __restrict__ out)
{
    __shared__ float cws[192*96];
    __shared__ float diff[TG][192];
    __shared__ float e1s[TG][64], e2s[TG][64];
    __shared__ float h1s[TG][96], h2s[TG][96];
    __shared__ float s1s[TG][16], s2s[TG][16], srep[TG][16];
    __shared__ float red[16][16][TG];

    int t = threadIdx.x;
    int b0 = blockIdx.x * TG;

    // inline layer-2 outer for BOTH sides
    {
        int b = t >> 5, o = (t & 31) * 2;
        const float* prq = pooled_q2 + (size_t)(b0 + b)*64;
        const float* prc = pooled_c2 + (size_t)(b0 + b)*64;
        float q0 = ob2[o], q1 = ob2[o+1];
        float c0 = ob2[o], c1 = ob2[o+1];
        for (int k = 0; k < 64; k++) {
            float w0 = ow2[k*64 + o], w1 = ow2[k*64 + o + 1];
            float pq = prq[k], pc = prc[k];
            q0 = fmaf(pq, w0, q0); q1 = fmaf(pq, w1, q1);
            c0 = fmaf(pc, w0, c0); c1 = fmaf(pc, w1, c1);
        }
        e1s[b][o]   = fmaxf(q0, 0.f);
        e1s[b][o+1] = fmaxf(q1, 0.f);
        e2s[b][o]   = fmaxf(c0, 0.f);
        e2s[b][o+1] = fmaxf(c1, 0.f);
    }
    for (int i = t; i < 192*96; i += 256) cws[i] = cw1[i];
    __syncthreads();

    for (int i = t; i < TG*192; i += 256) {
        int b = i / 192, f = i % 192;
        float qv = (f < 128) ? qf[(b0+b)*192 + f] : e1s[b][f-128];
        float cv = (f < 128) ? cf[(b0+b)*192 + f] : e2s[b][f-128];
        float d = qv - cv;
        diff[b][f] = __expf(-d*d);
    }
    __syncthreads();

    {
        int b = t >> 5, o = (t & 31) * 3;
        float a0 = cb1[o], a1 = cb1[o+1], a2 = cb1[o+2];
        for (int f = 0; f < 192; f++) {
            float d = diff[b][f];
            const float* w = cws + f*96 + o;
            a0 = fmaf(d, w[0], a0);
            a1 = fmaf(d, w[1], a1);
            a2 = fmaf(d, w[2], a2);
        }
        h1s[b][o] = fmaxf(a0, 0.f);
        h1s[b][o+1] = fmaxf(a1, 0.f);
        h1s[b][o+2] = fmaxf(a2, 0.f);
    }
    __syncthreads();
    for (int i = t; i < 96*96; i += 256) cws[i] = cw2[i];
    __syncthreads();
    {
        int b = t >> 5, o = (t & 31) * 3;
        float a0 = cb2[o], a1 = cb2[o+1], a2 = cb2[o+2];
        for (int f = 0; f < 96; f++) {
            float d = h1s[b][f];
            const float* w = cws + f*96 + o;
            a0 = fmaf(d, w[0], a0);
            a1 = fmaf(d, w[1], a1);
            a2 = fmaf(d, w[2], a2);
        }
        h2s[b][o] = tanhf(a0);
        h2s[b][o+1] = tanhf(a1);
        h2s[b][o+2] = tanhf(a2);
    }
    __syncthreads();
    if (t < TG*16) {
        int b = t >> 4, o = t & 15;
        float a = sb1[o];
        for (int f = 0; f < 96; f++) a = fmaf(h2s[b][f], sw1[f*16+o], a);
        s1s[b][o] = fmaxf(a, 0.f);
    }

    {
        int tt = t & 15, gq = t >> 4;
        int g0 = gq * 4;
        int lane = t & 63;
        float e1v[TG];
        #pragma unroll
        for (int b = 0; b < TG; b++) e1v[b] = e1s[b][lane];
        float v0[TG], v1[TG], v2[TG], v3[TG];
        #pragma unroll
        for (int b = 0; b < TG; b++) { v0[b]=0.f; v1[b]=0.f; v2[b]=0.f; v3[b]=0.f; }
        for (int f = 0; f < 64; f++) {
            const float* wp = nw + ((size_t)f*64 + g0)*16 + tt;
            float w0 = wp[0], w1 = wp[16], w2 = wp[32], w3 = wp[48];
            #pragma unroll
            for (int b = 0; b < TG; b++) {
                float e = __shfl(e1v[b], f, 64);
                v0[b] = fmaf(e, w0, v0[b]);
                v1[b] = fmaf(e, w1, v1[b]);
                v2[b] = fmaf(e, w2, v2[b]);
                v3[b] = fmaf(e, w3, v3[b]);
            }
        }
        #pragma unroll
        for (int b = 0; b < TG; b++) {
            float p = v0[b]*e2s[b][g0] + v1[b]*e2s[b][g0+1]
                    + v2[b]*e2s[b][g0+2] + v3[b]*e2s[b][g0+3];
            red[gq][tt][b] = p;
        }
    }
    __syncthreads();
    if (t < TG*16) {
        int b = t >> 4, tt = t & 15;
        float scv = 0.f;
        #pragma unroll
        for (int gq = 0; gq < 16; gq++) scv += red[gq][tt][b];
        float blk = nb[tt];
        for (int f = 0; f < 64; f++) blk = fmaf(e1s[b][f], nwb[tt*128 + f], blk);
        for (int f = 0; f < 64; f++) blk = fmaf(e2s[b][f], nwb[tt*128 + 64 + f], blk);
        srep[b][tt] = fmaxf(scv + blk, 0.f);
    }
    __syncthreads();
    if (t < TG*16) {
        int b = t >> 4, o = t & 15;
        float a = mb1[o];
        #pragma unroll
        for (int f = 0; f < 16; f++) a = fmaf(srep[b][f], mw1[f*16+o], a);
        s2s[b][o] = fmaxf(a, 0.f);
    }
    __syncthreads();
    if (t < TG) {
        float sco = sb2[0], sm = mb2[0];
        #pragma unroll
        for (int f = 0; f < 16; f++) {
            sco = fmaf(s1s[t][f], sw2[f], sco);
            sm  = fmaf(s2s[t][f], mw2[f], sm);
        }
        float score = 1.f / (1.f + __expf(-sco));
        float sim   = 1.f / (1.f + __expf(-sm));
        out[b0 + t] = alpha[0]*score + beta[0]*sim;
    }
}

// ==================================================================
// ===================== SPLIT PATH (r6, proven) ====================
// ==================================================================
__global__ __launch_bounds__(256) void k_zero(int* __restrict__ cnt,
    const float* __restrict__ pooled_prev, const float* __restrict__ owp,
    const float* __restrict__ obp, float* __restrict__ feats_prev)
{
    int i = blockIdx.x*256 + threadIdx.x;
    if (i < NN) cnt[i] = 0;
    if (pooled_prev && blockIdx.x < 256) {
        int bb = i >> 6, j = i & 63;
        const float* pr = pooled_prev + bb*64;
        float a = obp[j];
        for (int k = 0; k < 64; k++) a = fmaf(pr[k], owp[k*64 + j], a);
        feats_prev[bb*192 + 128 + j] = fmaxf(a, 0.f);
    }
}

__global__ __launch_bounds__(256) void k_hist(const int* __restrict__ ei,
                                              int* __restrict__ cnt,
                                              int* __restrict__ rank)
{
    int e = blockIdx.x*256 + threadIdx.x;
    rank[e] = atomicAdd(cnt + ei[NEDGE + e], 1);
}

__global__ __launch_bounds__(256) void k_scan1(const int* __restrict__ cnt,
    int* __restrict__ rowptr, int* __restrict__ bsum)
{
    __shared__ int sd[256];
    int t = threadIdx.x;
    int base = blockIdx.x*1024 + t*4;
    int c0 = cnt[base], c1 = cnt[base+1], c2 = cnt[base+2], c3 = cnt[base+3];
    int tsum = c0 + c1 + c2 + c3;
    sd[t] = tsum;
    __syncthreads();
    for (int off = 1; off < 256; off <<= 1) {
        int v = (t >= off) ? sd[t-off] : 0;
        __syncthreads();
        sd[t] += v;
        __syncthreads();
    }
    int excl = sd[t] - tsum;
    rowptr[base]   = excl;
    rowptr[base+1] = excl + c0;
    rowptr[base+2] = excl + c0 + c1;
    rowptr[base+3] = excl + c0 + c1 + c2;
    if (t == 255) bsum[blockIdx.x] = sd[255];
}

__global__ __launch_bounds__(128) void k_scan2(const int* __restrict__ bsum,
    int* __restrict__ boff, int* __restrict__ rowptr)
{
    __shared__ int sd[128];
    int t = threadIdx.x;
    int v0 = bsum[t];
    sd[t] = v0;
    __syncthreads();
    for (int off = 1; off < 128; off <<= 1) {
        int v = (t >= off) ? sd[t-off] : 0;
        __syncthreads();
        sd[t] += v;
        __syncthreads();
    }
    boff[t] = sd[t] - v0;
    if (t == 0) rowptr[NN] = NEDGE;
}

__global__ __launch_bounds__(256) void k_scan3(int* __restrict__ rowptr,
    const int* __restrict__ boff)
{
    int i = blockIdx.x*256 + threadIdx.x;
    rowptr[i] += boff[i >> 10];
}

__global__ __launch_bounds__(256) void k_fill(const int* __restrict__ ei,
    const int* __restrict__ rowptr, const int* __restrict__ rank,
    int* __restrict__ col)
{
    int e = blockIdx.x*256 + threadIdx.x;
    int s = ei[e];
    int d = ei[NEDGE + e];
    col[rowptr[d] + rank[e]] = s;
}

__global__ __launch_bounds__(256) void k_cvt(const float* __restrict__ x,
                                             bf16* __restrict__ xh,
                                             float* __restrict__ zbuf)
{
    int i = blockIdx.x*256 + threadIdx.x;
    float4 v = ((const float4*)x)[i];
    short4 o;
    o.x = f2bf_s(v.x); o.y = f2bf_s(v.y);
    o.z = f2bf_s(v.z); o.w = f2bf_s(v.w);
    ((short4*)xh)[i] = o;
    if (i < 3*128 + 3*BG*64) zbuf[i] = 0.f;
}

__global__ __launch_bounds__(256) void k_agg_gin(
    const bf16* __restrict__ xh,
    const int* __restrict__ rowptr, const int* __restrict__ col,
    const float* __restrict__ epsp,
    const short* __restrict__ w1h, const short* __restrict__ w1l,
    const float* __restrict__ b1,
    const short* __restrict__ w2h, const short* __restrict__ w2l,
    const float* __restrict__ b2,
    unsigned short* __restrict__ bigh, float* __restrict__ stats,
    const float* __restrict__ pooled_prev, const float* __restrict__ owp,
    const float* __restrict__ obp, float* __restrict__ feats, int coffp)
{
    __shared__ __align__(16) char buf[4][9472];
    __shared__ float red[2][4][64];
    int tid = threadIdx.x, wv = tid >> 6, lane = tid & 63;
    int q = lane >> 4, m = lane & 15;
    int nb = blockIdx.x*128 + wv*32;
    short* Sh = (short*)buf[wv];
    short* Sl = Sh + 2304;
    float ep = 1.0f + *epsp;

    if (pooled_prev && blockIdx.x < 256) {
        int g = blockIdx.x*256 + tid;
        int bb = g >> 6, j = g & 63;
        const float* pr = pooled_prev + bb*64;
        float a = obp[j];
        for (int k = 0; k < 64; k++) a = fmaf(pr[k], owp[k*64 + j], a);
        feats[bb*192 + coffp + j] = fmaxf(a, 0.f);
    }

    int gv = rowptr[nb + (lane < 33 ? lane : 32)];
    int fo = m * 4;
    const unsigned short* xt = (const unsigned short*)xh;

    for (int i = 0; i < 8; i++) {
        int row = i*4 + q;
        int rs = __shfl(gv, row, 64);
        int re = __shfl(gv, row+1, 64);
        float a0=0.f,a1=0.f,a2=0.f,a3=0.f;
        float e0=0.f,e1=0.f,e2=0.f,e3=0.f;
        float g0=0.f,g1=0.f,g2=0.f,g3=0.f;
        float h0=0.f,h1=0.f,h2=0.f,h3=0.f;
        int r = rs;
        for (; r + 4 <= re; r += 4) {
            int ca = col[r], cb = col[r+1], cc = col[r+2], cd = col[r+3];
            acc4(xt + (((size_t)ca) << 6) + fo, a0,a1,a2,a3);
            acc4(xt + (((size_t)cb) << 6) + fo, e0,e1,e2,e3);
            acc4(xt + (((size_t)cc) << 6) + fo, g0,g1,g2,g3);
            acc4(xt + (((size_t)cd) << 6) + fo, h0,h1,h2,h3);
        }
        for (; r < re; r++)
            acc4(xt + (((size_t)col[r]) << 6) + fo, a0,a1,a2,a3);
        a0 += e0 + g0 + h0;
        a1 += e1 + g1 + h1;
        a2 += e2 + g2 + h2;
        a3 += e3 + g3 + h3;
        ushort4 sv = *(const ushort4*)(xt + (((size_t)(nb+row)) << 6) + fo);
        a0 = fmaf(ep, bf2f_s((short)sv.x), a0);
        a1 = fmaf(ep, bf2f_s((short)sv.y), a1);
        a2 = fmaf(ep, bf2f_s((short)sv.z), a2);
        a3 = fmaf(ep, bf2f_s((short)sv.w), a3);
        short4 hh, ll;
        hh.x = f2bf_s(a0); ll.x = f2bf_s(a0 - bf2f_s(hh.x));
        hh.y = f2bf_s(a1); ll.y = f2bf_s(a1 - bf2f_s(hh.y));
        hh.z = f2bf_s(a2); ll.z = f2bf_s(a2 - bf2f_s(hh.z));
        hh.w = f2bf_s(a3); ll.w = f2bf_s(a3 - bf2f_s(hh.w));
        *(short4*)(Sh + row*72 + fo) = hh;
        *(short4*)(Sl + row*72 + fo) = ll;
    }
    __syncthreads();

    short8 Ah[2][2], Al[2][2];
    #pragma unroll
    for (int mc=0; mc<2; mc++)
      #pragma unroll
      for (int kc=0; kc<2; kc++){
        Ah[mc][kc] = *(const short8*)(Sh + (mc*16+m)*72 + kc*32 + q*8);
        Al[mc][kc] = *(const short8*)(Sl + (mc*16+m)*72 + kc*32 + q*8);
      }
    floatx4 acc[2][4];
    #pragma unroll
    for (int mc=0;mc<2;mc++)
      #pragma unroll
      for (int nc=0;nc<4;nc++) acc[mc][nc] = (floatx4){0.f,0.f,0.f,0.f};
    #pragma unroll
    for (int nc=0;nc<4;nc++){
      #pragma unroll
      for (int kc=0;kc<2;kc++){
        short8 bh = *(const short8*)(w1h + (nc*16+m)*64 + kc*32 + q*8);
        short8 bl = *(const short8*)(w1l + (nc*16+m)*64 + kc*32 + q*8);
        #pragma unroll
        for (int mc=0;mc<2;mc++){
          acc[mc][nc] = __builtin_amdgcn_mfma_f32_16x16x32_bf16(Ah[mc][kc], bh, acc[mc][nc],0,0,0);
          acc[mc][nc] = __builtin_amdgcn_mfma_f32_16x16x32_bf16(Al[mc][kc], bh, acc[mc][nc],0,0,0);
          acc[mc][nc] = __builtin_amdgcn_mfma_f32_16x16x32_bf16(Ah[mc][kc], bl, acc[mc][nc],0,0,0);
        }
      }
    }

    #pragma unroll
    for (int nc=0;nc<4;nc++){
      float bia = b1[nc*16+m];
      #pragma unroll
      for (int mc=0;mc<2;mc++)
        #pragma unroll
        for (int r=0;r<4;r++){
          float v = fmaxf(acc[mc][nc][r] + bia, 0.f);
          int row = mc*16 + q*4 + r, cl = nc*16 + m;
          short hb = f2bf_s(v);
          Sh[row*72+cl] = hb;
          Sl[row*72+cl] = f2bf_s(v - bf2f_s(hb));
        }
    }
    __syncthreads();

    short8 A2h[2][2], A2l[2][2];
    #pragma unroll
    for (int mc=0; mc<2; mc++)
      #pragma unroll
      for (int kc=0; kc<2; kc++){
        A2h[mc][kc] = *(const short8*)(Sh + (mc*16+m)*72 + kc*32 + q*8);
        A2l[mc][kc] = *(const short8*)(Sl + (mc*16+m)*72 + kc*32 + q*8);
      }
    floatx4 acc2[2][4];
    #pragma unroll
    for (int mc=0;mc<2;mc++)
      #pragma unroll
      for (int nc=0;nc<4;nc++) acc2[mc][nc] = (floatx4){0.f,0.f,0.f,0.f};
    #pragma unroll
    for (int nc=0;nc<4;nc++){
      #pragma unroll
      for (int kc=0;kc<2;kc++){
        short8 bh = *(const short8*)(w2h + (nc*16+m)*64 + kc*32 + q*8);
        short8 bl = *(const short8*)(w2l + (nc*16+m)*64 + kc*32 + q*8);
        #pragma unroll
        for (int mc=0;mc<2;mc++){
          acc2[mc][nc] = __builtin_amdgcn_mfma_f32_16x16x32_bf16(A2h[mc][kc], bh, acc2[mc][nc],0,0,0);
          acc2[mc][nc] = __builtin_amdgcn_mfma_f32_16x16x32_bf16(A2l[mc][kc], bh, acc2[mc][nc],0,0,0);
          acc2[mc][nc] = __builtin_amdgcn_mfma_f32_16x16x32_bf16(A2h[mc][kc], bl, acc2[mc][nc],0,0,0);
        }
      }
    }

    #pragma unroll
    for (int nc=0;nc<4;nc++){
      float bia = b2[nc*16+m];
      float s = 0.f, s2 = 0.f;
      #pragma unroll
      for (int mc=0;mc<2;mc++)
        #pragma unroll
        for (int r=0;r<4;r++){
          float v = acc2[mc][nc][r] + bia;
          bigh[(((size_t)(nb + mc*16 + q*4 + r)) << 6) + nc*16 + m] =
              (unsigned short)f2bf_s(v);
          s += v; s2 = fmaf(v, v, s2);
        }
      s  += __shfl_xor(s, 16, 64);  s  += __shfl_xor(s, 32, 64);
      s2 += __shfl_xor(s2,16, 64);  s2 += __shfl_xor(s2,32, 64);
      if (q == 0){ red[0][wv][nc*16+m] = s; red[1][wv][nc*16+m] = s2; }
    }
    __syncthreads();
    if (tid < 128){
      int which = tid >> 6, c = tid & 63;
      float a = red[which][0][c]+red[which][1][c]+red[which][2][c]+red[which][3][c];
      unsafeAtomicAdd(stats + which*64 + c, a);
    }
}

__global__ __launch_bounds__(256) void k_bn_inner(
    const unsigned short* __restrict__ bigh, const float* __restrict__ stats,
    const float* __restrict__ gam, const float* __restrict__ bet,
    const short* __restrict__ wih, const short* __restrict__ wil,
    const float* __restrict__ bi,
    bf16* __restrict__ xh,
    const int* __restrict__ gidx, float* __restrict__ pooled)
{
    __shared__ __align__(16) char buf[4][9472];
    int tid = threadIdx.x, wv = tid >> 6, lane = tid & 63;
    int q = lane >> 4, m = lane & 15;
    int nb = blockIdx.x*128 + wv*32;
    short* Sh = (short*)buf[wv];
    short* Sl = Sh + 2304;

    float mu  = stats[lane]    * (1.0f/NN);
    float ex2 = stats[64+lane] * (1.0f/NN);
    float var = ex2 - mu*mu;
    float sc  = gam[lane] * rsqrtf(var + 1e-5f);
    float sh  = bet[lane] - mu*sc;

    for (int rr = 0; rr < 32; rr++){
        float v = bf2f_s((short)bigh[(((size_t)(nb+rr)) << 6) + lane]);
        v = fmaxf(fmaf(v, sc, sh), 0.f);
        xh[(((size_t)(nb+rr)) << 6) + lane] = __float2bfloat16(v);
        short hb = f2bf_s(v);
        Sh[rr*72 + lane] = hb;
        Sl[rr*72 + lane] = f2bf_s(v - bf2f_s(hb));
    }
    __syncthreads();

    short8 A2h[2][2], A2l[2][2];
    #pragma unroll
    for (int mc=0; mc<2; mc++)
      #pragma unroll
      for (int kc=0; kc<2; kc++){
        A2h[mc][kc] = *(const short8*)(Sh + (mc*16+m)*72 + kc*32 + q*8);
        A2l[mc][kc] = *(const short8*)(Sl + (mc*16+m)*72 + kc*32 + q*8);
      }
    floatx4 acc[2][4];
    #pragma unroll
    for (int mc=0;mc<2;mc++)
      #pragma unroll
      for (int nc=0;nc<4;nc++) acc[mc][nc] = (floatx4){0.f,0.f,0.f,0.f};
    #pragma unroll
    for (int nc=0;nc<4;nc++){
      #pragma unroll
      for (int kc=0;kc<2;kc++){
        short8 bh = *(const short8*)(wih + (nc*16+m)*64 + kc*32 + q*8);
        short8 bl = *(const short8*)(wil + (nc*16+m)*64 + kc*32 + q*8);
        #pragma unroll
        for (int mc=0;mc<2;mc++){
          acc[mc][nc] = __builtin_amdgcn_mfma_f32_16x16x32_bf16(A2h[mc][kc], bh, acc[mc][nc],0,0,0);
          acc[mc][nc] = __builtin_amdgcn_mfma_f32_16x16x32_bf16(A2l[mc][kc], bh, acc[mc][nc],0,0,0);
          acc[mc][nc] = __builtin_amdgcn_mfma_f32_16x16x32_bf16(A2h[mc][kc], bl, acc[mc][nc],0,0,0);
        }
      }
    }
    __syncthreads();

    float* P = (float*)buf[wv];
    #pragma unroll
    for (int nc=0;nc<4;nc++){
      float bia = bi[nc*16+m];
      #pragma unroll
      for (int mc=0;mc<2;mc++)
        #pragma unroll
        for (int r=0;r<4;r++){
          float v = fmaxf(acc[mc][nc][r] + bia, 0.f);
          P[(mc*16 + q*4 + r)*66 + nc*16 + m] = v;
        }
    }
    __syncthreads();

    int gv = (lane < 32) ? gidx[nb + lane] : 0;
    int cur = __shfl(gv, 0, 64);
    float a = 0.f;
    for (int rr = 0; rr < 32; rr++){
        int g = __shfl(gv, rr, 64);
        if (g != cur){
            unsafeAtomicAdd(pooled + (size_t)cur*64 + lane, a);
            a = 0.f; cur = g;
        }
        a += P[rr*66 + lane];
    }
    unsafeAtomicAdd(pooled + (size_t)cur*64 + lane, a);
}

__global__ __launch_bounds__(256) void k_tail(
    const float* __restrict__ qf, const float* __restrict__ cf,
    const float* __restrict__ pooled_c2,
    const float* __restrict__ ow2, const float* __restrict__ ob2,
    const float* __restrict__ cw1, const float* __restrict__ cb1,
    const float* __restrict__ cw2, const float* __restrict__ cb2,
    const float* __restrict__ sw1, const float* __restrict__ sb1,
    const float* __restrict__ sw2, const float* __restrict__ sb2,
    const float* __restrict__ nw,  const float* __restrict__ nwb,
    const float* __restrict__ nb,
    const float* __restrict__ mw1, const float* __restrict__ mb1,
    const float* __restrict__ mw2, const float* __restrict__ mb2,
    const float* __restrict__ alpha, const float* __restrict__ beta,
    float* __restrict__ out)
{
    __shared__ float cws[192*96];
    __shared__ float diff[TG][192];
    __shared__ float e1s[TG][64], e2s[TG][64];
    __shared__ float h1s[TG][96], h2s[TG][96];
    __shared__ float s1s[TG][16], s2s[TG][16], srep[TG][16];
    __shared__ float red[16][16][TG];

    int t = threadIdx.x;
    int b0 = blockIdx.x * TG;

    {
        int b = t >> 5, o = (t & 31) * 2;
        const float* pr = pooled_c2 + (size_t)(b0 + b)*64;
        float a0 = ob2[o], a1 = ob2[o+1];
        for (int k = 0; k < 64; k++) {
            float p = pr[k];
            a0 = fmaf(p, ow2[k*64 + o], a0);
            a1 = fmaf(p, ow2[k*64 + o + 1], a1);
        }
        e2s[b][o]   = fmaxf(a0, 0.f);
        e2s[b][o+1] = fmaxf(a1, 0.f);
    }
    for (int i = t; i < 192*96; i += 256) cws[i] = cw1[i];
    __syncthreads();

    for (int i = t; i < TG*192; i += 256) {
        int b = i / 192, f = i % 192;
        float qv = qf[(b0+b)*192 + f];
        float cv = (f < 128) ? cf[(b0+b)*192 + f] : e2s[b][f-128];
        float d = qv - cv;
        diff[b][f] = __expf(-d*d);
        if (f >= 128) e1s[b][f-128] = qv;
    }
    __syncthreads();

    {
        int b = t >> 5, o = (t & 31) * 3;
        float a0 = cb1[o], a1 = cb1[o+1], a2 = cb1[o+2];
        for (int f = 0; f < 192; f++) {
            float d = diff[b][f];
            const float* w = cws + f*96 + o;
            a0 = fmaf(d, w[0], a0);
            a1 = fmaf(d, w[1], a1);
            a2 = fmaf(d, w[2], a2);
        }
        h1s[b][o] = fmaxf(a0, 0.f);
        h1s[b][o+1] = fmaxf(a1, 0.f);
        h1s[b][o+2] = fmaxf(a2, 0.f);
    }
    __syncthreads();
    for (int i = t; i < 96*96; i += 256) cws[i] = cw2[i];
    __syncthreads();
    {
        int b = t >> 5, o = (t & 31) * 3;
        float a0 = cb2[o], a1 = cb2[o+1], a2 = cb2[o+2];
        for (int f = 0; f < 96; f++) {
            float d = h1s[b][f];
            const float* w = cws + f*96 + o;
            a0 = fmaf(d, w[0], a0);
            a1 = fmaf(d, w[1], a1);
            a2 = fmaf(d, w[2], a2);
        }
        h2s[b][o] = tanhf(a0);
        h2s[b][o+1] = tanhf(a1);
        h2s[b][o+2] = tanhf(a2);
    }
    __syncthreads();
    if (t < TG*16) {
        int b = t >> 4, o = t & 15;
        float a = sb1[o];
        for (int f = 0; f < 96; f++) a = fmaf(h2s[b][f], sw1[f*16+o], a);
        s1s[b][o] = fmaxf(a, 0.f);
    }

    {
        int tt = t & 15, gq = t >> 4;
        int g0 = gq * 4;
        int lane = t & 63;
        float e1v[TG];
        #pragma unroll
        for (int b = 0; b < TG; b++) e1v[b] = e1s[b][lane];
        float v0[TG], v1[TG], v2[TG], v3[TG];
        #pragma unroll
        for (int b = 0; b < TG; b++) { v0[b]=0.f; v1[b]=0.f; v2[b]=0.f; v3[b]=0.f; }
        for (int f = 0; f < 64; f++) {
            const float* wp = nw + ((size_t)f*64 + g0)*16 + tt;
            float w0 = wp[0], w1 = wp[16], w2 = wp[32], w3 = wp[48];
            #pragma unroll
            for (int b = 0; b < TG; b++) {
                float e = __shfl(e1v[b], f, 64);
                v0[b] = fmaf(e, w0, v0[b]);
                v1[b] = fmaf(e, w1, v1[b]);
                v2[b] = fmaf(e, w2, v2[b]);
                v3[b] = fmaf(e, w3, v3[b]);
            }
        }
        #pragma unroll
        for (int b = 0; b < TG; b++) {
            float p = v0[b]*e2s[b][g0] + v1[b]*e2s[b][g0+1]
                    + v2[b]*e2s[b][g0+2] + v3[b]*e2s[b][g0+3];
            red[gq][tt][b] = p;
        }
    }
    __syncthreads();
    if (t < TG*16) {
        int b = t >> 4, tt = t & 15;
        float scv = 0.f;
        #pragma unroll
        for (int gq = 0; gq < 16; gq++) scv += red[gq][tt][b];
        float blk = nb[tt];
        for (int f = 0; f < 64; f++) blk = fmaf(e1s[b][f], nwb[tt*128 + f], blk);
        for (int f = 0; f < 64; f++) blk = fmaf(e2s[b][f], nwb[tt*128 + 64 + f], blk);
        srep[b][tt] = fmaxf(scv + blk, 0.f);
    }
    __syncthreads();
    if (t < TG*16) {
        int b = t >> 4, o = t & 15;
        float a = mb1[o];
        #pragma unroll
        for (int f = 0; f < 16; f++) a = fmaf(srep[b][f], mw1[f*16+o], a);
        s2s[b][o] = fmaxf(a, 0.f);
    }
    __syncthreads();
    if (t < TG) {
        float sco = sb2[0], sm = mb2[0];
        #pragma unroll
        for (int f = 0; f < 16; f++) {
            sco = fmaf(s1s[t][f], sw2[f], sco);
            sm  = fmaf(s2s[t][f], mw2[f], sm);
        }
        float score = 1.f / (1.f + __expf(-sco));
        float sim   = 1.f / (1.f + __expf(-sm));
        out[b0 + t] = alpha[0]*score + beta[0]*sim;
    }
}

// ------------------------------------------------------------------
extern "C" void kernel_launch(void* const* d_in, const int* in_sizes, int n_in,
                              void* d_out, int out_size, void* d_ws, size_t ws_size,
                              hipStream_t stream)
{
    const float* qx  = (const float*)d_in[0];
    const float* cx  = (const float*)d_in[1];
    const int*   qei = (const int*)d_in[2];
    const int*   cei = (const int*)d_in[3];
    const int*   qgi = (const int*)d_in[4];
    const int*   cgi = (const int*)d_in[5];
    const float* Wgw1 = (const float*)d_in[6];
    const float* Wgb1 = (const float*)d_in[7];
    const float* Wgw2 = (const float*)d_in[8];
    const float* Wgb2 = (const float*)d_in[9];
    const float* Wgam = (const float*)d_in[10];
    const float* Wbet = (const float*)d_in[11];
    const float* Weps = (const float*)d_in[12];
    const float* Wiw  = (const float*)d_in[13];
    const float* Wib  = (const float*)d_in[14];
    const float* Wow  = (const float*)d_in[15];
    const float* Wob  = (const float*)d_in[16];
    const float* Wcw1 = (const float*)d_in[17];
    const float* Wcb1 = (const float*)d_in[18];
    const float* Wcw2 = (const float*)d_in[19];
    const float* Wcb2 = (const float*)d_in[20];
    const float* Wsw1 = (const float*)d_in[21];
    const float* Wsb1 = (const float*)d_in[22];
    const float* Wsw2 = (const float*)d_in[23];
    const float* Wsb2 = (const float*)d_in[24];
    const float* Wnw  = (const float*)d_in[25];
    const float* Wnwb = (const float*)d_in[26];
    const float* Wnb  = (const float*)d_in[27];
    const float* Wmw1 = (const float*)d_in[28];
    const float* Wmb1 = (const float*)d_in[29];
    const float* Wmw2 = (const float*)d_in[30];
    const float* Wmb2 = (const float*)d_in[31];
    const float* Wal  = (const float*)d_in[32];
    const float* Wbe  = (const float*)d_in[33];

    float* F = (float*)d_ws;

    // Merged path needs ~81 MB; guard with margin.
    const size_t MERGED_NEED = 86ull << 20;

    if (ws_size >= MERGED_NEED) {
        // ---------------- merged-graph path (13 dispatches) ----------------
        unsigned short* bigh = (unsigned short*)F;     // 2NN*64 bf16 = 33.5 MB
        int*   rank   = (int*)F;                       // 2M ints, aliases bigh
        bf16*  xh     = (bf16*)(F + 8388608);          // 2NN*64 bf16 = 33.5 MB
        float* zbuf   = F + 16777216;                  // ZTOTM floats
        float* stats3 = zbuf;                          // 2x3x128
        float* pooled3= zbuf + 768;                    // (side*3+l)*BG*64
        float* qf     = F + 16777216 + ZTOTM;          // BG*192
        float* cf     = qf + 196608;                   // BG*192
        int*   rowptr = (int*)(cf + 196608);           // 2NN+1
        int*   cnt    = rowptr + (2*NN + 1);           // 2NN
        int*   col    = cnt + 2*NN;                    // 2M
        int*   bsum   = col + 2*NEDGE;                 // 256
        int*   boff   = bsum + 256;                    // 256
        uintptr_t wtb = (uintptr_t)(boff + 256);
        wtb = (wtb + 63) & ~((uintptr_t)63);
        short* w1h = (short*)wtb;
        short* w1l = w1h + 3*4096;
        short* w2h = w1l + 3*4096;
        short* w2l = w2h + 3*4096;
        short* wih = w2l + 3*4096;
        short* wil = wih + 3*4096;

        k_wprep<<<144, 256, 0, stream>>>(Wgw1, Wgw2, Wiw, w1h, w1l, w2h, w2l, wih, wil);
        k_cvtM  <<<16384, 256, 0, stream>>>(qx, cx, xh, cnt, zbuf);
        k_histM <<<8192, 256, 0, stream>>>(qei, cei, cnt, rank);
        k_scan1M<<<256, 256, 0, stream>>>(cnt, rowptr, bsum);
        k_scan2M<<<1, 256, 0, stream>>>(bsum, boff, rowptr);
        k_scan3M<<<1024, 256, 0, stream>>>(rowptr, boff);
        k_fillM <<<8192, 256, 0, stream>>>(qei, cei, rowptr, rank, col);

        for (int l = 0; l < LAYERS; l++) {
            const float* ppq = (l == 0) ? nullptr : pooled3 + (size_t)(l-1)*BG*64;
            const float* ppc = (l == 0) ? nullptr : pooled3 + (size_t)(3 + l-1)*BG*64;
            const float* owp = (l == 0) ? nullptr : Wow + (l-1)*4096;
            const float* obp = (l == 0) ? nullptr : Wob + (l-1)*64;
            k_agg_ginM<<<2048, 256, 0, stream>>>(xh, rowptr, col, Weps + l,
                                                 w1h + l*4096, w1l + l*4096, Wgb1 + l*64,
                                                 w2h + l*4096, w2l + l*4096, Wgb2 + l*64,
                                                 bigh, stats3 + l*256,
                                                 ppq, ppc, owp, obp,
                                                 qf, cf, (l-1)*64);
            k_bn_innerM<<<2048, 256, 0, stream>>>(bigh, stats3 + l*256,
                                                  Wgam + l*64, Wbet + l*64,
                                                  wih + l*4096, wil + l*4096,
                                                  Wib + l*64, xh, qgi, cgi,
                                                  pooled3 + (size_t)l*BG*64,
                                                  pooled3 + (size_t)(3 + l)*BG*64);
        }

        k_tailM<<<BG/TG, 256, 0, stream>>>(qf, cf,
                                           pooled3 + (size_t)2*BG*64,
                                           pooled3 + (size_t)5*BG*64,
                                           Wow + 2*4096, Wob + 2*64,
                                           Wcw1, Wcb1, Wcw2, Wcb2,
                                           Wsw1, Wsb1, Wsw2, Wsb2,
                                           Wnw, Wnwb, Wnb, Wmw1, Wmb1, Wmw2, Wmb2,
                                           Wal, Wbe, (float*)d_out);
        return;
    }

    // ---------------- split path (r6-exact, proven 908 us) ----------------
    unsigned short* bigh = (unsigned short*)F;    // NN*64 bf16; rank aliases
    int*   rank   = (int*)F;
    float* zbuf   = F + 8388608;
    float* stats3 = zbuf;
    float* pooled3= zbuf + 384;
    float* qf     = pooled3 + 3*BG*64;
    float* cf     = qf + 196608;
    int*   rowptr = (int*)(cf + 196608);
    int*   cnt    = rowptr + (NN + 1);
    int*   col    = cnt + NN;
    int*   bsum   = col + NEDGE;
    int*   boff   = bsum + 128;
    bf16*  xh     = (bf16*)(boff + 128);
    uintptr_t wtb = (uintptr_t)(xh + (size_t)NN*64);
    wtb = (wtb + 63) & ~((uintptr_t)63);
    short* w1h = (short*)wtb;
    short* w1l = w1h + 3*4096;
    short* w2h = w1l + 3*4096;
    short* w2l = w2h + 3*4096;
    short* wih = w2l + 3*4096;
    short* wil = wih + 3*4096;

    k_wprep<<<144, 256, 0, stream>>>(Wgw1, Wgw2, Wiw, w1h, w1l, w2h, w2l, wih, wil);

    for (int side = 0; side < 2; side++) {
        const float* x0 = side ? cx  : qx;
        const int* ei   = side ? cei : qei;
        const int* gi   = side ? cgi : qgi;
        float* feats    = side ? cf  : qf;

        if (side == 0)
            k_zero<<<NN/256, 256, 0, stream>>>(cnt, nullptr, nullptr, nullptr, nullptr);
        else
            k_zero<<<NN/256, 256, 0, stream>>>(cnt, pooled3 + 2*BG*64,
                                               Wow + 2*4096, Wob + 2*64, qf);
        k_hist<<<NEDGE/256, 256, 0, stream>>>(ei, cnt, rank);
        k_scan1<<<128, 256, 0, stream>>>(cnt, rowptr, bsum);
        k_scan2<<<1, 128, 0, stream>>>(bsum, boff, rowptr);
        k_scan3<<<NN/256, 256, 0, stream>>>(rowptr, boff);
        k_fill<<<NEDGE/256, 256, 0, stream>>>(ei, rowptr, rank, col);

        k_cvt<<<NN*64/1024, 256, 0, stream>>>(x0, xh, zbuf);

        for (int l = 0; l < LAYERS; l++) {
            const float* pprev = (l == 0) ? nullptr : pooled3 + (size_t)(l-1)*BG*64;
            const float* owp   = (l == 0) ? nullptr : Wow + (l-1)*4096;
            const float* obp   = (l == 0) ? nullptr : Wob + (l-1)*64;
            k_agg_gin<<<NN/128, 256, 0, stream>>>(xh, rowptr, col, Weps + l,
                                                  w1h + l*4096, w1l + l*4096, Wgb1 + l*64,
                                                  w2h + l*4096, w2l + l*4096, Wgb2 + l*64,
                                                  bigh, stats3 + l*128,
                                                  pprev, owp, obp, feats, (l-1)*64);
            k_bn_inner<<<NN/128, 256, 0, stream>>>(bigh, stats3 + l*128,
                                                   Wgam + l*64, Wbet + l*64,
                                                   wih + l*4096, wil + l*4096,
                                                   Wib + l*64, xh, gi,
                                                   pooled3 + (size_t)l*BG*64);
        }
    }

    k_tail<<<BG/TG, 256, 0, stream>>>(qf, cf, pooled3 + 2*BG*64,
                                      Wow + 2*4096, Wob + 2*64,
                                      Wcw1, Wcb1, Wcw2, Wcb2,
                                      Wsw1, Wsb1, Wsw2, Wsb2,
                                      Wnw, Wnwb, Wnb, Wmw1, Wmb1, Wmw2, Wmb2,
                                      Wal, Wbe, (float*)d_out);
}